// Round 2
// baseline (1696.041 us; speedup 1.0000x reference)
//
#include <hip/hip_runtime.h>
#include <hip/hip_bf16.h>

#define NUU 50000
#define NMM 20000
#define FEAT 32
#define NE 262144
#define NEL 100000
#define HD 512
#define EDIM 7
#define NC 7

typedef __hip_bfloat16 bf16;

__device__ __forceinline__ float b2f(unsigned short u)
{
  return __uint_as_float((unsigned)u << 16);
}
__device__ __forceinline__ unsigned short f2bbits(float x)
{
  __hip_bfloat16 h = __float2bfloat16(x);
  return *reinterpret_cast<unsigned short*>(&h);
}
__device__ __forceinline__ float2 ld2(const float* p) { return *(const float2*)p; }
__device__ __forceinline__ float2 ld2(const bf16* p)
{
  ushort2 u = *(const ushort2*)p;
  return make_float2(b2f(u.x), b2f(u.y));
}
__device__ __forceinline__ float4 ld4(const float* p) { return *(const float4*)p; }
__device__ __forceinline__ float4 ld4(const bf16* p)
{
  ushort4 u = *(const ushort4*)p;
  return make_float4(b2f(u.x), b2f(u.y), b2f(u.z), b2f(u.w));
}
__device__ __forceinline__ void st2b(bf16* p, float x, float y)
{
  ushort2 u = make_ushort2(f2bbits(x), f2bbits(y));
  *(ushort2*)p = u;
}
__device__ __forceinline__ void st4b(bf16* p, float4 v)
{
  ushort4 u = make_ushort4(f2bbits(v.x), f2bbits(v.y), f2bbits(v.z), f2bbits(v.w));
  *(ushort4*)p = u;
}

// ---------------- encoder: x_m = movie_x @ mlw + mlb + movie_emb (bf16 out) ----------------
__global__ __launch_bounds__(256) void encoder_k(
    const float* __restrict__ mx, const float* __restrict__ W,
    const float* __restrict__ b, const float* __restrict__ emb,
    bf16* __restrict__ xm)
{
  const int m = blockIdx.x;
  const int tid = threadIdx.x;
  const int c0 = 2 * tid;
  __shared__ float xr[FEAT];
  if (tid < FEAT) xr[tid] = mx[(size_t)m * FEAT + tid];
  __syncthreads();
  float2 e2 = ld2(&emb[(size_t)m * HD + c0]);
  float s0 = b[c0] + e2.x;
  float s1 = b[c0 + 1] + e2.y;
#pragma unroll
  for (int k = 0; k < FEAT; ++k) {
    float2 w2 = ld2(&W[(size_t)k * HD + c0]);
    s0 += xr[k] * w2.x;
    s1 += xr[k] * w2.y;
  }
  st2b(&xm[(size_t)m * HD + c0], s0, s1);
}

// ---------------- CSR build ----------------
__global__ void count_k(const int* __restrict__ dst, int* __restrict__ cnt, int n)
{
  for (int i = blockIdx.x * blockDim.x + threadIdx.x; i < n; i += gridDim.x * blockDim.x)
    atomicAdd(&cnt[dst[i]], 1);
}

__global__ void scan_a(const int* __restrict__ in, int* __restrict__ out,
                       int* __restrict__ bsum, int n)
{
  __shared__ int s[256];
  const int tid = threadIdx.x;
  const int i = blockIdx.x * 256 + tid;
  int v = (i < n) ? in[i] : 0;
  s[tid] = v;
  __syncthreads();
  for (int d = 1; d < 256; d <<= 1) {
    int t = (tid >= d) ? s[tid - d] : 0;
    __syncthreads();
    s[tid] += t;
    __syncthreads();
  }
  if (i < n) out[i] = s[tid] - v;           // exclusive
  if (tid == 255) bsum[blockIdx.x] = s[255];
}

__global__ void scan_b(int* __restrict__ bsum, int nb)
{
  __shared__ int s[256];
  const int tid = threadIdx.x;
  int v = (tid < nb) ? bsum[tid] : 0;
  s[tid] = v;
  __syncthreads();
  for (int d = 1; d < 256; d <<= 1) {
    int t = (tid >= d) ? s[tid - d] : 0;
    __syncthreads();
    s[tid] += t;
    __syncthreads();
  }
  if (tid < nb) bsum[tid] = s[tid] - v;     // exclusive
}

__global__ void scan_c(int* __restrict__ out, const int* __restrict__ bsum, int n)
{
  const int i = blockIdx.x * 256 + threadIdx.x;
  if (i < n) out[i] += bsum[blockIdx.x];
}

__global__ void fill_k(const int* __restrict__ dst, const int* __restrict__ off,
                       int* __restrict__ fill, int* __restrict__ csr, int n)
{
  for (int i = blockIdx.x * blockDim.x + threadIdx.x; i < n; i += gridDim.x * blockDim.x) {
    int d = dst[i];
    int p = off[d] + atomicAdd(&fill[d], 1);
    csr[p] = i;
  }
}

// ---- folded classifier weights: Wl' = lw@cls, Wr' = rw@cls, cc = lb@cls ----
__global__ __launch_bounds__(64) void projw_k(
    const float* __restrict__ lw, const float* __restrict__ rw,
    const float* __restrict__ lb, const float* __restrict__ clsW,
    float* __restrict__ Wl, float* __restrict__ Wr, float* __restrict__ cc)
{
  const int k = blockIdx.x;
  const int l = threadIdx.x;
  if (k < HD) {
    float aL[NC] = {0, 0, 0, 0, 0, 0, 0};
    float aR[NC] = {0, 0, 0, 0, 0, 0, 0};
    for (int j = l; j < HD; j += 64) {
      float a = lw[(size_t)k * HD + j];
      float b = rw[(size_t)k * HD + j];
#pragma unroll
      for (int c = 0; c < NC; ++c) {
        float w = clsW[(size_t)j * NC + c];
        aL[c] += a * w;
        aR[c] += b * w;
      }
    }
#pragma unroll
    for (int c = 0; c < NC; ++c)
      for (int s = 32; s; s >>= 1) {
        aL[c] += __shfl_xor(aL[c], s);
        aR[c] += __shfl_xor(aR[c], s);
      }
    if (l == 0) {
#pragma unroll
      for (int c = 0; c < NC; ++c) {
        Wl[k * NC + c] = aL[c];
        Wr[k * NC + c] = aR[c];
      }
    }
  } else {
    float a0[NC] = {0, 0, 0, 0, 0, 0, 0};
    for (int j = l; j < HD; j += 64) {
      float a = lb[j];
#pragma unroll
      for (int c = 0; c < NC; ++c) a0[c] += a * clsW[(size_t)j * NC + c];
    }
#pragma unroll
    for (int c = 0; c < NC; ++c)
      for (int s = 32; s; s >>= 1) a0[c] += __shfl_xor(a0[c], s);
    if (l == 0) {
#pragma unroll
      for (int c = 0; c < NC; ++c) cc[c] = a0[c];
    }
  }
}

// ---- layer-1 SpMM + fused edge transform: t[d] bf16 out ----
template <typename TS>
__global__ __launch_bounds__(256) void spmm_t(
    const TS* __restrict__ xsrc, const int* __restrict__ esrc,
    const int* __restrict__ csr, const int* __restrict__ off,
    const int* __restrict__ cnt, const float* __restrict__ ea,
    const float* __restrict__ ew, const float* __restrict__ eb,
    bf16* __restrict__ t)
{
  const int d = blockIdx.x;
  const int tid = threadIdx.x;
  const int c0 = 2 * tid;
  const int deg = cnt[d];
  const int start = off[d];
  float a0 = 0.f, a1 = 0.f, eacc = 0.f;
  for (int i = 0; i < deg; ++i) {
    int e = csr[start + i];
    int s = esrc[e];
    float2 v = ld2(&xsrc[(size_t)s * HD + c0]);
    a0 += v.x;
    a1 += v.y;
    if (tid < EDIM) eacc += ea[(size_t)e * EDIM + tid];
  }
  __shared__ float sea[EDIM];
  if (tid < EDIM) sea[tid] = eacc;
  __syncthreads();
  float o0 = 0.f, o1 = 0.f;
  if (deg > 0) {
    float inv = 1.f / (float)deg;
    float s0 = a0, s1 = a1;
#pragma unroll
    for (int k = 0; k < EDIM; ++k) {
      float2 w2 = ld2(&ew[(size_t)k * HD + c0]);
      s0 += sea[k] * w2.x;
      s1 += sea[k] * w2.y;
    }
    o0 = s0 * inv + eb[c0];
    o1 = s1 * inv + eb[c0 + 1];
  }
  st2b(&t[(size_t)d * HD + c0], o0, o1);
}

// ---- layer-2 SpMM fused with folded classifier projection: P[d][0..6] ----
__global__ __launch_bounds__(256) void spmm_proj(
    const bf16* __restrict__ srcfeat, const bf16* __restrict__ ownfeat,
    const int* __restrict__ esrc, const int* __restrict__ csr,
    const int* __restrict__ off, const int* __restrict__ cnt,
    const float* __restrict__ ea, const float* __restrict__ ew,
    const float* __restrict__ eb, const float* __restrict__ Wl,
    const float* __restrict__ Wr, const float* __restrict__ cc,
    float* __restrict__ P)
{
  const int d = blockIdx.x;
  const int tid = threadIdx.x;
  const int c0 = 2 * tid;
  const int deg = cnt[d];
  const int start = off[d];
  float a0 = 0.f, a1 = 0.f, eacc = 0.f;
  for (int i = 0; i < deg; ++i) {
    int e = csr[start + i];
    int s = esrc[e];
    float2 v = ld2(&srcfeat[(size_t)s * HD + c0]);
    a0 += v.x;
    a1 += v.y;
    if (tid < EDIM) eacc += ea[(size_t)e * EDIM + tid];
  }
  __shared__ float sea[EDIM];
  if (tid < EDIM) sea[tid] = eacc;
  __syncthreads();
  float t0 = 0.f, t1 = 0.f;
  if (deg > 0) {
    float inv = 1.f / (float)deg;
    float s0 = a0, s1 = a1;
#pragma unroll
    for (int k = 0; k < EDIM; ++k) {
      float2 w2 = ld2(&ew[(size_t)k * HD + c0]);
      s0 += sea[k] * w2.x;
      s1 += sea[k] * w2.y;
    }
    t0 = s0 * inv + eb[c0];
    t1 = s1 * inv + eb[c0 + 1];
  }
  float2 own = ld2(&ownfeat[(size_t)d * HD + c0]);
  float p[NC];
#pragma unroll
  for (int c = 0; c < NC; ++c)
    p[c] = t0 * Wl[c0 * NC + c] + t1 * Wl[(c0 + 1) * NC + c] +
           own.x * Wr[c0 * NC + c] + own.y * Wr[(c0 + 1) * NC + c];
#pragma unroll
  for (int c = 0; c < NC; ++c)
    for (int s = 32; s; s >>= 1) p[c] += __shfl_xor(p[c], s);
  __shared__ float red[4][NC];
  const int w = tid >> 6;
  if ((tid & 63) == 0) {
#pragma unroll
    for (int c = 0; c < NC; ++c) red[w][c] = p[c];
  }
  __syncthreads();
  if (tid == 0) {
#pragma unroll
    for (int c = 0; c < NC; ++c)
      P[(size_t)d * NC + c] = red[0][c] + red[1][c] + red[2][c] + red[3][c] + cc[c];
  }
}

// ---- fused conv output GEMM: O = A1@B1 + A2@B2 + bias (+relu), bf16 out ----
template <typename TA1, typename TA2>
__global__ __launch_bounds__(256) void gemm_fused(
    const TA1* __restrict__ A1, const TA2* __restrict__ A2,
    const float* __restrict__ B1, const float* __restrict__ B2,
    const float* __restrict__ bias, bf16* __restrict__ O,
    int M, int do_relu)
{
  __shared__ float As[16][128];
  __shared__ float Bs[16][64];
  const int tid = threadIdx.x;
  const int tx = tid & 15;
  const int ty = tid >> 4;
  const int m0 = blockIdx.x * 128;
  const int n0 = blockIdx.y * 64;

  const int arow0 = tid >> 2;          // 0..63
  const int akq0 = (tid & 3) * 4;      // k offset within 16
  const int arow1 = arow0 + 64;        // 64..127
  const int bkk = tid >> 4;
  const int bnq = (tid & 15) * 4;

  float acc[8][4];
#pragma unroll
  for (int i = 0; i < 8; ++i)
#pragma unroll
    for (int j = 0; j < 4; ++j) acc[i][j] = 0.f;

  for (int k0 = 0; k0 < 2 * HD; k0 += 16) {
    const int kc = k0 & (HD - 1);

    float4 va0 = make_float4(0.f, 0.f, 0.f, 0.f);
    float4 va1 = va0;
    if (k0 < HD) {
      if (m0 + arow0 < M) va0 = ld4(&A1[(size_t)(m0 + arow0) * HD + kc + akq0]);
      if (m0 + arow1 < M) va1 = ld4(&A1[(size_t)(m0 + arow1) * HD + kc + akq0]);
    } else {
      if (m0 + arow0 < M) va0 = ld4(&A2[(size_t)(m0 + arow0) * HD + kc + akq0]);
      if (m0 + arow1 < M) va1 = ld4(&A2[(size_t)(m0 + arow1) * HD + kc + akq0]);
    }
    const float* __restrict__ Bp = (k0 < HD) ? B1 : B2;
    float4 vb = *(const float4*)&Bp[(size_t)(kc + bkk) * HD + n0 + bnq];

    __syncthreads();
    As[akq0 + 0][arow0] = va0.x; As[akq0 + 1][arow0] = va0.y;
    As[akq0 + 2][arow0] = va0.z; As[akq0 + 3][arow0] = va0.w;
    As[akq0 + 0][arow1] = va1.x; As[akq0 + 1][arow1] = va1.y;
    As[akq0 + 2][arow1] = va1.z; As[akq0 + 3][arow1] = va1.w;
    *(float4*)&Bs[bkk][bnq] = vb;
    __syncthreads();

#pragma unroll
    for (int kk = 0; kk < 16; ++kk) {
      float4 a0 = *(const float4*)&As[kk][8 * ty];
      float4 a1 = *(const float4*)&As[kk][8 * ty + 4];
      float4 b4 = *(const float4*)&Bs[kk][4 * tx];
      float a[8] = {a0.x, a0.y, a0.z, a0.w, a1.x, a1.y, a1.z, a1.w};
      float b[4] = {b4.x, b4.y, b4.z, b4.w};
#pragma unroll
      for (int i = 0; i < 8; ++i)
#pragma unroll
        for (int j = 0; j < 4; ++j) acc[i][j] += a[i] * b[j];
    }
  }

  float bsv[4];
#pragma unroll
  for (int j = 0; j < 4; ++j) bsv[j] = bias[n0 + 4 * tx + j];

#pragma unroll
  for (int i = 0; i < 8; ++i) {
    int row = m0 + 8 * ty + i;
    if (row < M) {
      float v0 = acc[i][0] + bsv[0];
      float v1 = acc[i][1] + bsv[1];
      float v2 = acc[i][2] + bsv[2];
      float v3 = acc[i][3] + bsv[3];
      if (do_relu) {
        v0 = fmaxf(v0, 0.f); v1 = fmaxf(v1, 0.f);
        v2 = fmaxf(v2, 0.f); v3 = fmaxf(v3, 0.f);
      }
      st4b(&O[(size_t)row * HD + n0 + 4 * tx], make_float4(v0, v1, v2, v3));
    }
  }
}

__global__ void gather_out_k(const float* __restrict__ Pu, const float* __restrict__ Pm,
                             const int* __restrict__ eli, const float* __restrict__ cb,
                             float* __restrict__ out)
{
  const int i = blockIdx.x * 256 + threadIdx.x;
  if (i >= NEL * NC) return;
  int e = i / NC;
  int c = i - e * NC;
  out[i] = Pu[(size_t)eli[e] * NC + c] + Pm[(size_t)eli[NEL + e] * NC + c] + cb[c];
}

// ---------------- host side ----------------
static inline char* bump(char*& p, size_t bytes)
{
  char* r = p;
  p += (bytes + 255) & ~(size_t)255;
  return r;
}

extern "C" void kernel_launch(void* const* d_in, const int* in_sizes, int n_in,
                              void* d_out, int out_size, void* d_ws, size_t ws_size,
                              hipStream_t stream)
{
  const float* movie_x   = (const float*)d_in[0];
  const float* user_emb  = (const float*)d_in[1];
  const float* movie_emb = (const float*)d_in[2];
  const float* mlw       = (const float*)d_in[3];
  const float* mlb       = (const float*)d_in[4];
  const float* ea_um     = (const float*)d_in[5];
  const float* ea_mu     = (const float*)d_in[6];
  const float* mu1_lw = (const float*)d_in[7];
  const float* mu1_lb = (const float*)d_in[8];
  const float* mu1_rw = (const float*)d_in[9];
  const float* mu1_ew = (const float*)d_in[10];
  const float* mu1_eb = (const float*)d_in[11];
  const float* um1_lw = (const float*)d_in[12];
  const float* um1_lb = (const float*)d_in[13];
  const float* um1_rw = (const float*)d_in[14];
  const float* um1_ew = (const float*)d_in[15];
  const float* um1_eb = (const float*)d_in[16];
  const float* mu2_lw = (const float*)d_in[17];
  const float* mu2_lb = (const float*)d_in[18];
  const float* mu2_rw = (const float*)d_in[19];
  const float* mu2_ew = (const float*)d_in[20];
  const float* mu2_eb = (const float*)d_in[21];
  const float* um2_lw = (const float*)d_in[22];
  const float* um2_lb = (const float*)d_in[23];
  const float* um2_rw = (const float*)d_in[24];
  const float* um2_ew = (const float*)d_in[25];
  const float* um2_eb = (const float*)d_in[26];
  const float* cls_w  = (const float*)d_in[27];
  const float* cls_b  = (const float*)d_in[28];
  const int*   ei_um  = (const int*)d_in[29];   // [2, E]: src(user), dst(movie)
  const int*   ei_mu  = (const int*)d_in[30];   // [2, E]: src(movie), dst(user)
  const int*   eli    = (const int*)d_in[31];   // [2, EL]
  float* out = (float*)d_out;

  char* w = (char*)d_ws;
  bf16* x_m  = (bf16*)bump(w, (size_t)NMM * HD * 2);
  bf16* tbuf = (bf16*)bump(w, (size_t)NUU * HD * 2);
  bf16* u1   = (bf16*)bump(w, (size_t)NUU * HD * 2);
  bf16* m1   = (bf16*)bump(w, (size_t)NMM * HD * 2);
  float* Pu  = (float*)bump(w, (size_t)NUU * NC * 4);
  float* Pm  = (float*)bump(w, (size_t)NMM * NC * 4);
  float* Wl_u = (float*)bump(w, (size_t)HD * NC * 4);
  float* Wr_u = (float*)bump(w, (size_t)HD * NC * 4);
  float* cc_u = (float*)bump(w, 64 * 4);
  float* Wl_m = (float*)bump(w, (size_t)HD * NC * 4);
  float* Wr_m = (float*)bump(w, (size_t)HD * NC * 4);
  float* cc_m = (float*)bump(w, 64 * 4);
  int* cf     = (int*)bump(w, (size_t)(2 * NUU + 2 * NMM) * 4);
  int* cnt_u  = cf;
  int* fill_u = cf + NUU;
  int* cnt_m  = cf + 2 * NUU;
  int* fill_m = cf + 2 * NUU + NMM;
  int* off_u  = (int*)bump(w, (size_t)NUU * 4);
  int* off_m  = (int*)bump(w, (size_t)NMM * 4);
  int* bsum   = (int*)bump(w, 256 * 4);
  int* csr_mu = (int*)bump(w, (size_t)NE * 4);
  int* csr_um = (int*)bump(w, (size_t)NE * 4);

  const int GU = (NUU + 255) / 256;   // 196
  const int GM = (NMM + 255) / 256;   // 79

  hipMemsetAsync(cf, 0, (size_t)(2 * NUU + 2 * NMM) * 4, stream);

  encoder_k<<<NMM, 256, 0, stream>>>(movie_x, mlw, mlb, movie_emb, x_m);

  count_k<<<1024, 256, 0, stream>>>(ei_mu + NE, cnt_u, NE);
  count_k<<<1024, 256, 0, stream>>>(ei_um + NE, cnt_m, NE);
  scan_a<<<GU, 256, 0, stream>>>(cnt_u, off_u, bsum, NUU);
  scan_b<<<1, 256, 0, stream>>>(bsum, GU);
  scan_c<<<GU, 256, 0, stream>>>(off_u, bsum, NUU);
  scan_a<<<GM, 256, 0, stream>>>(cnt_m, off_m, bsum, NMM);
  scan_b<<<1, 256, 0, stream>>>(bsum, GM);
  scan_c<<<GM, 256, 0, stream>>>(off_m, bsum, NMM);
  fill_k<<<1024, 256, 0, stream>>>(ei_mu + NE, off_u, fill_u, csr_mu, NE);
  fill_k<<<1024, 256, 0, stream>>>(ei_um + NE, off_m, fill_m, csr_um, NE);

  projw_k<<<HD + 1, 64, 0, stream>>>(mu2_lw, mu2_rw, mu2_lb, cls_w, Wl_u, Wr_u, cc_u);
  projw_k<<<HD + 1, 64, 0, stream>>>(um2_lw, um2_rw, um2_lb, cls_w + (size_t)HD * NC,
                                     Wl_m, Wr_m, cc_m);

  const dim3 gu((NUU + 127) / 128, HD / 64);   // 391 x 8
  const dim3 gm((NMM + 127) / 128, HD / 64);   // 157 x 8

  // layer 1: u1 = relu(conv(x_m -> users))
  spmm_t<bf16><<<NUU, 256, 0, stream>>>(x_m, ei_mu, csr_mu, off_u, cnt_u, ea_mu,
                                        mu1_ew, mu1_eb, tbuf);
  gemm_fused<bf16, float><<<gu, 256, 0, stream>>>(tbuf, user_emb, mu1_lw, mu1_rw,
                                                  mu1_lb, u1, NUU, 1);
  // layer 1: m1 = relu(conv(x_u -> movies))
  spmm_t<float><<<NMM, 256, 0, stream>>>(user_emb, ei_um, csr_um, off_m, cnt_m, ea_um,
                                         um1_ew, um1_eb, tbuf);
  gemm_fused<bf16, bf16><<<gm, 256, 0, stream>>>(tbuf, x_m, um1_lw, um1_rw,
                                                 um1_lb, m1, NMM, 1);
  // layer 2 fused with classifier projection (u2/m2 never materialized)
  spmm_proj<<<NUU, 256, 0, stream>>>(m1, u1, ei_mu, csr_mu, off_u, cnt_u, ea_mu,
                                     mu2_ew, mu2_eb, Wl_u, Wr_u, cc_u, Pu);
  spmm_proj<<<NMM, 256, 0, stream>>>(u1, m1, ei_um, csr_um, off_m, cnt_m, ea_um,
                                     um2_ew, um2_eb, Wl_m, Wr_m, cc_m, Pm);

  gather_out_k<<<(NEL * NC + 255) / 256, 256, 0, stream>>>(Pu, Pm, eli, cls_b, out);
}

// Round 3
// 923.003 us; speedup vs baseline: 1.8375x; 1.8375x over previous
//
#include <hip/hip_runtime.h>
#include <hip/hip_bf16.h>

#define NUU 50000
#define NMM 20000
#define FEAT 32
#define NE 262144
#define NEL 100000
#define HD 512
#define EDIM 7
#define NC 7

typedef __hip_bfloat16 bf16;
typedef __attribute__((ext_vector_type(8))) short short8;
typedef __attribute__((ext_vector_type(4))) float f32x4;

__device__ __forceinline__ float b2f(unsigned short u)
{
  return __uint_as_float((unsigned)u << 16);
}
__device__ __forceinline__ unsigned short f2bbits(float x)
{
  __hip_bfloat16 h = __float2bfloat16(x);
  return *reinterpret_cast<unsigned short*>(&h);
}
__device__ __forceinline__ float2 ld2(const float* p) { return *(const float2*)p; }
__device__ __forceinline__ float2 ld2(const bf16* p)
{
  ushort2 u = *(const ushort2*)p;
  return make_float2(b2f(u.x), b2f(u.y));
}
__device__ __forceinline__ void st2b(bf16* p, float x, float y)
{
  ushort2 u = make_ushort2(f2bbits(x), f2bbits(y));
  *(ushort2*)p = u;
}
__device__ __forceinline__ void gload16(const void* g, void* l)
{
  __builtin_amdgcn_global_load_lds(
      (const __attribute__((address_space(1))) void*)g,
      (__attribute__((address_space(3))) void*)l, 16, 0, 0);
}

// ---------------- encoder: x_m = movie_x @ mlw + mlb + movie_emb (bf16 out) ----------------
__global__ __launch_bounds__(256) void encoder_k(
    const float* __restrict__ mx, const float* __restrict__ W,
    const float* __restrict__ b, const float* __restrict__ emb,
    bf16* __restrict__ xm)
{
  const int m = blockIdx.x;
  const int tid = threadIdx.x;
  const int c0 = 2 * tid;
  __shared__ float xr[FEAT];
  if (tid < FEAT) xr[tid] = mx[(size_t)m * FEAT + tid];
  __syncthreads();
  float2 e2 = ld2(&emb[(size_t)m * HD + c0]);
  float s0 = b[c0] + e2.x;
  float s1 = b[c0 + 1] + e2.y;
#pragma unroll
  for (int k = 0; k < FEAT; ++k) {
    float2 w2 = ld2(&W[(size_t)k * HD + c0]);
    s0 += xr[k] * w2.x;
    s1 += xr[k] * w2.y;
  }
  st2b(&xm[(size_t)m * HD + c0], s0, s1);
}

// ---------------- prep: fp32 -> bf16 copy ----------------
__global__ __launch_bounds__(256) void cvt_bf16_k(const float* __restrict__ in,
                                                  bf16* __restrict__ out, int n4)
{
  for (int i = blockIdx.x * 256 + threadIdx.x; i < n4; i += gridDim.x * 256) {
    float4 v = *(const float4*)&in[4 * (size_t)i];
    ushort4 u = make_ushort4(f2bbits(v.x), f2bbits(v.y), f2bbits(v.z), f2bbits(v.w));
    *(ushort4*)&out[4 * (size_t)i] = u;
  }
}

// ---------------- prep: Wcat[n][k] = (k<512 ? lw[k][n] : rw[k-512][n]) as bf16 ----------------
__global__ __launch_bounds__(256) void wtrans_k(const float* __restrict__ lw,
                                                const float* __restrict__ rw,
                                                bf16* __restrict__ Wcat)
{
  __shared__ float s[32][33];
  const int tx = threadIdx.x & 31;
  const int ty = threadIdx.x >> 5;      // 0..7
  const int nt = blockIdx.x * 32;       // n tile
  const int kt = blockIdx.y * 32;       // k tile (0..1023)
#pragma unroll
  for (int q = 0; q < 4; ++q) {
    int k = kt + q * 8 + ty;
    int n = nt + tx;
    float v = (k < HD) ? lw[(size_t)k * HD + n] : rw[(size_t)(k - HD) * HD + n];
    s[q * 8 + ty][tx] = v;
  }
  __syncthreads();
#pragma unroll
  for (int q = 0; q < 4; ++q) {
    int n = nt + q * 8 + ty;
    int k = kt + tx;
    Wcat[(size_t)n * (2 * HD) + k] = __float2bfloat16(s[tx][q * 8 + ty]);
  }
}

// ---------------- CSR build ----------------
__global__ void count_k(const int* __restrict__ dst, int* __restrict__ cnt, int n)
{
  for (int i = blockIdx.x * blockDim.x + threadIdx.x; i < n; i += gridDim.x * blockDim.x)
    atomicAdd(&cnt[dst[i]], 1);
}

__global__ void scan_a(const int* __restrict__ in, int* __restrict__ out,
                       int* __restrict__ bsum, int n)
{
  __shared__ int s[256];
  const int tid = threadIdx.x;
  const int i = blockIdx.x * 256 + tid;
  int v = (i < n) ? in[i] : 0;
  s[tid] = v;
  __syncthreads();
  for (int d = 1; d < 256; d <<= 1) {
    int t = (tid >= d) ? s[tid - d] : 0;
    __syncthreads();
    s[tid] += t;
    __syncthreads();
  }
  if (i < n) out[i] = s[tid] - v;           // exclusive
  if (tid == 255) bsum[blockIdx.x] = s[255];
}

__global__ void scan_b(int* __restrict__ bsum, int nb)
{
  __shared__ int s[256];
  const int tid = threadIdx.x;
  int v = (tid < nb) ? bsum[tid] : 0;
  s[tid] = v;
  __syncthreads();
  for (int d = 1; d < 256; d <<= 1) {
    int t = (tid >= d) ? s[tid - d] : 0;
    __syncthreads();
    s[tid] += t;
    __syncthreads();
  }
  if (tid < nb) bsum[tid] = s[tid] - v;     // exclusive
}

__global__ void scan_c(int* __restrict__ out, const int* __restrict__ bsum, int n)
{
  const int i = blockIdx.x * 256 + threadIdx.x;
  if (i < n) out[i] += bsum[blockIdx.x];
}

__global__ void fill_k(const int* __restrict__ dst, const int* __restrict__ off,
                       int* __restrict__ fill, int* __restrict__ csr, int n)
{
  for (int i = blockIdx.x * blockDim.x + threadIdx.x; i < n; i += gridDim.x * blockDim.x) {
    int d = dst[i];
    int p = off[d] + atomicAdd(&fill[d], 1);
    csr[p] = i;
  }
}

// ---- folded classifier weights: Wl' = lw@cls, Wr' = rw@cls, cc = lb@cls ----
__global__ __launch_bounds__(64) void projw_k(
    const float* __restrict__ lw, const float* __restrict__ rw,
    const float* __restrict__ lb, const float* __restrict__ clsW,
    float* __restrict__ Wl, float* __restrict__ Wr, float* __restrict__ cc)
{
  const int k = blockIdx.x;
  const int l = threadIdx.x;
  if (k < HD) {
    float aL[NC] = {0, 0, 0, 0, 0, 0, 0};
    float aR[NC] = {0, 0, 0, 0, 0, 0, 0};
    for (int j = l; j < HD; j += 64) {
      float a = lw[(size_t)k * HD + j];
      float b = rw[(size_t)k * HD + j];
#pragma unroll
      for (int c = 0; c < NC; ++c) {
        float w = clsW[(size_t)j * NC + c];
        aL[c] += a * w;
        aR[c] += b * w;
      }
    }
#pragma unroll
    for (int c = 0; c < NC; ++c)
      for (int s = 32; s; s >>= 1) {
        aL[c] += __shfl_xor(aL[c], s);
        aR[c] += __shfl_xor(aR[c], s);
      }
    if (l == 0) {
#pragma unroll
      for (int c = 0; c < NC; ++c) {
        Wl[k * NC + c] = aL[c];
        Wr[k * NC + c] = aR[c];
      }
    }
  } else {
    float a0[NC] = {0, 0, 0, 0, 0, 0, 0};
    for (int j = l; j < HD; j += 64) {
      float a = lb[j];
#pragma unroll
      for (int c = 0; c < NC; ++c) a0[c] += a * clsW[(size_t)j * NC + c];
    }
#pragma unroll
    for (int c = 0; c < NC; ++c)
      for (int s = 32; s; s >>= 1) a0[c] += __shfl_xor(a0[c], s);
    if (l == 0) {
#pragma unroll
      for (int c = 0; c < NC; ++c) cc[c] = a0[c];
    }
  }
}

// ---- layer-1 SpMM + fused edge transform: t[d] bf16 out ----
template <typename TS>
__global__ __launch_bounds__(256) void spmm_t(
    const TS* __restrict__ xsrc, const int* __restrict__ esrc,
    const int* __restrict__ csr, const int* __restrict__ off,
    const int* __restrict__ cnt, const float* __restrict__ ea,
    const float* __restrict__ ew, const float* __restrict__ eb,
    bf16* __restrict__ t)
{
  const int d = blockIdx.x;
  const int tid = threadIdx.x;
  const int c0 = 2 * tid;
  const int deg = cnt[d];
  const int start = off[d];
  float a0 = 0.f, a1 = 0.f, eacc = 0.f;
  for (int i = 0; i < deg; ++i) {
    int e = csr[start + i];
    int s = esrc[e];
    float2 v = ld2(&xsrc[(size_t)s * HD + c0]);
    a0 += v.x;
    a1 += v.y;
    if (tid < EDIM) eacc += ea[(size_t)e * EDIM + tid];
  }
  __shared__ float sea[EDIM];
  if (tid < EDIM) sea[tid] = eacc;
  __syncthreads();
  float o0 = 0.f, o1 = 0.f;
  if (deg > 0) {
    float inv = 1.f / (float)deg;
    float s0 = a0, s1 = a1;
#pragma unroll
    for (int k = 0; k < EDIM; ++k) {
      float2 w2 = ld2(&ew[(size_t)k * HD + c0]);
      s0 += sea[k] * w2.x;
      s1 += sea[k] * w2.y;
    }
    o0 = s0 * inv + eb[c0];
    o1 = s1 * inv + eb[c0 + 1];
  }
  st2b(&t[(size_t)d * HD + c0], o0, o1);
}

// ---- layer-2 SpMM fused with folded classifier projection: P[d][0..6] ----
__global__ __launch_bounds__(256) void spmm_proj(
    const bf16* __restrict__ srcfeat, const bf16* __restrict__ ownfeat,
    const int* __restrict__ esrc, const int* __restrict__ csr,
    const int* __restrict__ off, const int* __restrict__ cnt,
    const float* __restrict__ ea, const float* __restrict__ ew,
    const float* __restrict__ eb, const float* __restrict__ Wl,
    const float* __restrict__ Wr, const float* __restrict__ cc,
    float* __restrict__ P)
{
  const int d = blockIdx.x;
  const int tid = threadIdx.x;
  const int c0 = 2 * tid;
  const int deg = cnt[d];
  const int start = off[d];
  float a0 = 0.f, a1 = 0.f, eacc = 0.f;
  for (int i = 0; i < deg; ++i) {
    int e = csr[start + i];
    int s = esrc[e];
    float2 v = ld2(&srcfeat[(size_t)s * HD + c0]);
    a0 += v.x;
    a1 += v.y;
    if (tid < EDIM) eacc += ea[(size_t)e * EDIM + tid];
  }
  __shared__ float sea[EDIM];
  if (tid < EDIM) sea[tid] = eacc;
  __syncthreads();
  float t0 = 0.f, t1 = 0.f;
  if (deg > 0) {
    float inv = 1.f / (float)deg;
    float s0 = a0, s1 = a1;
#pragma unroll
    for (int k = 0; k < EDIM; ++k) {
      float2 w2 = ld2(&ew[(size_t)k * HD + c0]);
      s0 += sea[k] * w2.x;
      s1 += sea[k] * w2.y;
    }
    t0 = s0 * inv + eb[c0];
    t1 = s1 * inv + eb[c0 + 1];
  }
  float2 own = ld2(&ownfeat[(size_t)d * HD + c0]);
  float p[NC];
#pragma unroll
  for (int c = 0; c < NC; ++c)
    p[c] = t0 * Wl[c0 * NC + c] + t1 * Wl[(c0 + 1) * NC + c] +
           own.x * Wr[c0 * NC + c] + own.y * Wr[(c0 + 1) * NC + c];
#pragma unroll
  for (int c = 0; c < NC; ++c)
    for (int s = 32; s; s >>= 1) p[c] += __shfl_xor(p[c], s);
  __shared__ float red[4][NC];
  const int w = tid >> 6;
  if ((tid & 63) == 0) {
#pragma unroll
    for (int c = 0; c < NC; ++c) red[w][c] = p[c];
  }
  __syncthreads();
  if (tid == 0) {
#pragma unroll
    for (int c = 0; c < NC; ++c)
      P[(size_t)d * NC + c] = red[0][c] + red[1][c] + red[2][c] + red[3][c] + cc[c];
  }
}

// ---- MFMA GEMM (m97 structure): O = [A1|A2](bf16,[M,512] each) @ Wcat^T + bias, bf16 out
// Wcat is [512 n][1024 k] bf16.  Tile 128x128, BK=32, 4 waves (2x2 of 64x64).
__global__ __launch_bounds__(256) void gemm_mfma(
    const bf16* __restrict__ A1, const bf16* __restrict__ A2,
    const bf16* __restrict__ Wcat, const float* __restrict__ bias,
    bf16* __restrict__ O, int M, int relu)
{
  __shared__ char lds[16384];       // A tile [128][32] bf16 @0, B tile [128][32] bf16 @8192
  const int tid = threadIdx.x;
  const int lane = tid & 63;
  const int wid = tid >> 6;
  const int wr = wid >> 1, wc = wid & 1;
  const int lr = lane & 15, lk = lane >> 4;
  const int m0 = blockIdx.x * 128;
  const int n0 = blockIdx.y * 128;

  const int srow = tid >> 2;        // 0..63 (staging row within half-tile)
  const int sslot = tid & 3;        // 16B slot within 64B row

  f32x4 acc[4][4];
#pragma unroll
  for (int i = 0; i < 4; ++i)
#pragma unroll
    for (int j = 0; j < 4; ++j) acc[i][j] = (f32x4){0.f, 0.f, 0.f, 0.f};

  int gr0 = m0 + srow;       if (gr0 >= M) gr0 = M - 1;
  int gr1 = m0 + srow + 64;  if (gr1 >= M) gr1 = M - 1;
  const size_t aoff0 = (size_t)gr0 * HD + 8 * sslot;
  const size_t aoff1 = (size_t)gr1 * HD + 8 * sslot;
  const size_t boff0 = (size_t)(n0 + srow) * (2 * HD) + 8 * sslot;
  const size_t boff1 = (size_t)(n0 + srow + 64) * (2 * HD) + 8 * sslot;

  for (int ks = 0; ks < 32; ++ks) {
    const int k0 = ks * 32;
    const bf16* __restrict__ Ap = (k0 < HD) ? A1 : A2;
    const int ac = k0 & (HD - 1);
    gload16(Ap + aoff0 + ac, &lds[tid * 16]);
    gload16(Ap + aoff1 + ac, &lds[4096 + tid * 16]);
    gload16(Wcat + boff0 + k0, &lds[8192 + tid * 16]);
    gload16(Wcat + boff1 + k0, &lds[12288 + tid * 16]);
    __syncthreads();

    short8 af[4], bfr[4];
#pragma unroll
    for (int mf = 0; mf < 4; ++mf)
      af[mf] = *(const short8*)&lds[(wr * 64 + mf * 16 + lr) * 64 + lk * 16];
#pragma unroll
    for (int nf = 0; nf < 4; ++nf)
      bfr[nf] = *(const short8*)&lds[8192 + (wc * 64 + nf * 16 + lr) * 64 + lk * 16];
#pragma unroll
    for (int mf = 0; mf < 4; ++mf)
#pragma unroll
      for (int nf = 0; nf < 4; ++nf)
        acc[mf][nf] = __builtin_amdgcn_mfma_f32_16x16x32_bf16(
            af[mf], bfr[nf], acc[mf][nf], 0, 0, 0);
    __syncthreads();
  }

  const int colbase = n0 + wc * 64 + lr;
#pragma unroll
  for (int nf = 0; nf < 4; ++nf) {
    const int col = colbase + nf * 16;
    const float bv = bias[col];
#pragma unroll
    for (int mf = 0; mf < 4; ++mf) {
      const int rowb = m0 + wr * 64 + mf * 16 + lk * 4;
#pragma unroll
      for (int r = 0; r < 4; ++r) {
        const int row = rowb + r;
        if (row < M) {
          float v = acc[mf][nf][r] + bv;
          if (relu) v = fmaxf(v, 0.f);
          O[(size_t)row * HD + col] = __float2bfloat16(v);
        }
      }
    }
  }
}

__global__ void gather_out_k(const float* __restrict__ Pu, const float* __restrict__ Pm,
                             const int* __restrict__ eli, const float* __restrict__ cb,
                             float* __restrict__ out)
{
  const int i = blockIdx.x * 256 + threadIdx.x;
  if (i >= NEL * NC) return;
  int e = i / NC;
  int c = i - e * NC;
  out[i] = Pu[(size_t)eli[e] * NC + c] + Pm[(size_t)eli[NEL + e] * NC + c] + cb[c];
}

// ---------------- host side ----------------
static inline char* bump(char*& p, size_t bytes)
{
  char* r = p;
  p += (bytes + 255) & ~(size_t)255;
  return r;
}

extern "C" void kernel_launch(void* const* d_in, const int* in_sizes, int n_in,
                              void* d_out, int out_size, void* d_ws, size_t ws_size,
                              hipStream_t stream)
{
  const float* movie_x   = (const float*)d_in[0];
  const float* user_emb  = (const float*)d_in[1];
  const float* movie_emb = (const float*)d_in[2];
  const float* mlw       = (const float*)d_in[3];
  const float* mlb       = (const float*)d_in[4];
  const float* ea_um     = (const float*)d_in[5];
  const float* ea_mu     = (const float*)d_in[6];
  const float* mu1_lw = (const float*)d_in[7];
  const float* mu1_lb = (const float*)d_in[8];
  const float* mu1_rw = (const float*)d_in[9];
  const float* mu1_ew = (const float*)d_in[10];
  const float* mu1_eb = (const float*)d_in[11];
  const float* um1_lw = (const float*)d_in[12];
  const float* um1_lb = (const float*)d_in[13];
  const float* um1_rw = (const float*)d_in[14];
  const float* um1_ew = (const float*)d_in[15];
  const float* um1_eb = (const float*)d_in[16];
  const float* mu2_lw = (const float*)d_in[17];
  const float* mu2_lb = (const float*)d_in[18];
  const float* mu2_rw = (const float*)d_in[19];
  const float* mu2_ew = (const float*)d_in[20];
  const float* mu2_eb = (const float*)d_in[21];
  const float* um2_lw = (const float*)d_in[22];
  const float* um2_lb = (const float*)d_in[23];
  const float* um2_rw = (const float*)d_in[24];
  const float* um2_ew = (const float*)d_in[25];
  const float* um2_eb = (const float*)d_in[26];
  const float* cls_w  = (const float*)d_in[27];
  const float* cls_b  = (const float*)d_in[28];
  const int*   ei_um  = (const int*)d_in[29];   // [2, E]: src(user), dst(movie)
  const int*   ei_mu  = (const int*)d_in[30];   // [2, E]: src(movie), dst(user)
  const int*   eli    = (const int*)d_in[31];   // [2, EL]
  float* out = (float*)d_out;

  char* w = (char*)d_ws;
  bf16* x_m   = (bf16*)bump(w, (size_t)NMM * HD * 2);
  bf16* tbuf  = (bf16*)bump(w, (size_t)NUU * HD * 2);
  bf16* u1    = (bf16*)bump(w, (size_t)NUU * HD * 2);
  bf16* m1    = (bf16*)bump(w, (size_t)NMM * HD * 2);
  bf16* ue_bf = (bf16*)bump(w, (size_t)NUU * HD * 2);
  bf16* Wcat_u1 = (bf16*)bump(w, (size_t)HD * 2 * HD * 2);
  bf16* Wcat_m1 = (bf16*)bump(w, (size_t)HD * 2 * HD * 2);
  float* Pu   = (float*)bump(w, (size_t)NUU * NC * 4);
  float* Pm   = (float*)bump(w, (size_t)NMM * NC * 4);
  float* Wl_u = (float*)bump(w, (size_t)HD * NC * 4);
  float* Wr_u = (float*)bump(w, (size_t)HD * NC * 4);
  float* cc_u = (float*)bump(w, 64 * 4);
  float* Wl_m = (float*)bump(w, (size_t)HD * NC * 4);
  float* Wr_m = (float*)bump(w, (size_t)HD * NC * 4);
  float* cc_m = (float*)bump(w, 64 * 4);
  int* cf     = (int*)bump(w, (size_t)(2 * NUU + 2 * NMM) * 4);
  int* cnt_u  = cf;
  int* fill_u = cf + NUU;
  int* cnt_m  = cf + 2 * NUU;
  int* fill_m = cf + 2 * NUU + NMM;
  int* off_u  = (int*)bump(w, (size_t)NUU * 4);
  int* off_m  = (int*)bump(w, (size_t)NMM * 4);
  int* bsum   = (int*)bump(w, 256 * 4);
  int* csr_mu = (int*)bump(w, (size_t)NE * 4);
  int* csr_um = (int*)bump(w, (size_t)NE * 4);

  const int GU = (NUU + 255) / 256;   // 196
  const int GM = (NMM + 255) / 256;   // 79

  hipMemsetAsync(cf, 0, (size_t)(2 * NUU + 2 * NMM) * 4, stream);

  encoder_k<<<NMM, 256, 0, stream>>>(movie_x, mlw, mlb, movie_emb, x_m);
  cvt_bf16_k<<<2048, 256, 0, stream>>>(user_emb, ue_bf, NUU * HD / 4);
  {
    dim3 g(HD / 32, 2 * HD / 32);   // 16 x 32
    wtrans_k<<<g, 256, 0, stream>>>(mu1_lw, mu1_rw, Wcat_u1);
    wtrans_k<<<g, 256, 0, stream>>>(um1_lw, um1_rw, Wcat_m1);
  }

  count_k<<<1024, 256, 0, stream>>>(ei_mu + NE, cnt_u, NE);
  count_k<<<1024, 256, 0, stream>>>(ei_um + NE, cnt_m, NE);
  scan_a<<<GU, 256, 0, stream>>>(cnt_u, off_u, bsum, NUU);
  scan_b<<<1, 256, 0, stream>>>(bsum, GU);
  scan_c<<<GU, 256, 0, stream>>>(off_u, bsum, NUU);
  scan_a<<<GM, 256, 0, stream>>>(cnt_m, off_m, bsum, NMM);
  scan_b<<<1, 256, 0, stream>>>(bsum, GM);
  scan_c<<<GM, 256, 0, stream>>>(off_m, bsum, NMM);
  fill_k<<<1024, 256, 0, stream>>>(ei_mu + NE, off_u, fill_u, csr_mu, NE);
  fill_k<<<1024, 256, 0, stream>>>(ei_um + NE, off_m, fill_m, csr_um, NE);

  projw_k<<<HD + 1, 64, 0, stream>>>(mu2_lw, mu2_rw, mu2_lb, cls_w, Wl_u, Wr_u, cc_u);
  projw_k<<<HD + 1, 64, 0, stream>>>(um2_lw, um2_rw, um2_lb, cls_w + (size_t)HD * NC,
                                     Wl_m, Wr_m, cc_m);

  const dim3 gu((NUU + 127) / 128, HD / 128);   // 391 x 4
  const dim3 gm((NMM + 127) / 128, HD / 128);   // 157 x 4

  // layer 1: u1 = relu(conv(x_m -> users))
  spmm_t<bf16><<<NUU, 256, 0, stream>>>(x_m, ei_mu, csr_mu, off_u, cnt_u, ea_mu,
                                        mu1_ew, mu1_eb, tbuf);
  gemm_mfma<<<gu, 256, 0, stream>>>(tbuf, ue_bf, Wcat_u1, mu1_lb, u1, NUU, 1);
  // layer 1: m1 = relu(conv(x_u -> movies))
  spmm_t<float><<<NMM, 256, 0, stream>>>(user_emb, ei_um, csr_um, off_m, cnt_m, ea_um,
                                         um1_ew, um1_eb, tbuf);
  gemm_mfma<<<gm, 256, 0, stream>>>(tbuf, x_m, Wcat_m1, um1_lb, m1, NMM, 1);
  // layer 2 fused with classifier projection (u2/m2 never materialized)
  spmm_proj<<<NUU, 256, 0, stream>>>(m1, u1, ei_mu, csr_mu, off_u, cnt_u, ea_mu,
                                     mu2_ew, mu2_eb, Wl_u, Wr_u, cc_u, Pu);
  spmm_proj<<<NMM, 256, 0, stream>>>(u1, m1, ei_um, csr_um, off_m, cnt_m, ea_um,
                                     um2_ew, um2_eb, Wl_m, Wr_m, cc_m, Pm);

  gather_out_k<<<(NEL * NC + 255) / 256, 256, 0, stream>>>(Pu, Pm, eli, cls_b, out);
}

// Round 4
// 627.778 us; speedup vs baseline: 2.7017x; 1.4703x over previous
//
#include <hip/hip_runtime.h>
#include <hip/hip_bf16.h>

#define NUU 50000
#define NMM 20000
#define FEAT 32
#define NE 262144
#define NEL 100000
#define HD 512
#define EDIM 7
#define NC 7

typedef __hip_bfloat16 bf16;
typedef __attribute__((ext_vector_type(8))) short short8;
typedef __attribute__((ext_vector_type(4))) float f32x4;

__device__ __forceinline__ float b2f(unsigned short u)
{
  return __uint_as_float((unsigned)u << 16);
}
__device__ __forceinline__ unsigned short f2bbits(float x)
{
  __hip_bfloat16 h = __float2bfloat16(x);
  return *reinterpret_cast<unsigned short*>(&h);
}
__device__ __forceinline__ float2 ld2(const float* p) { return *(const float2*)p; }
__device__ __forceinline__ float2 ld2(const bf16* p)
{
  ushort2 u = *(const ushort2*)p;
  return make_float2(b2f(u.x), b2f(u.y));
}
__device__ __forceinline__ void st2b(bf16* p, float x, float y)
{
  ushort2 u = make_ushort2(f2bbits(x), f2bbits(y));
  *(ushort2*)p = u;
}
__device__ __forceinline__ void gload16(const void* g, void* l)
{
  __builtin_amdgcn_global_load_lds(
      (const __attribute__((address_space(1))) void*)g,
      (__attribute__((address_space(3))) void*)l, 16, 0, 0);
}

// ---------------- encoder: x_m = movie_x @ mlw + mlb + movie_emb (bf16 out) ----------------
__global__ __launch_bounds__(256) void encoder_k(
    const float* __restrict__ mx, const float* __restrict__ W,
    const float* __restrict__ b, const float* __restrict__ emb,
    bf16* __restrict__ xm)
{
  const int m = blockIdx.x;
  const int tid = threadIdx.x;
  const int c0 = 2 * tid;
  __shared__ float xr[FEAT];
  if (tid < FEAT) xr[tid] = mx[(size_t)m * FEAT + tid];
  __syncthreads();
  float2 e2 = ld2(&emb[(size_t)m * HD + c0]);
  float s0 = b[c0] + e2.x;
  float s1 = b[c0 + 1] + e2.y;
#pragma unroll
  for (int k = 0; k < FEAT; ++k) {
    float2 w2 = ld2(&W[(size_t)k * HD + c0]);
    s0 += xr[k] * w2.x;
    s1 += xr[k] * w2.y;
  }
  st2b(&xm[(size_t)m * HD + c0], s0, s1);
}

// ---------------- prep: fp32 -> bf16 copy ----------------
__global__ __launch_bounds__(256) void cvt_bf16_k(const float* __restrict__ in,
                                                  bf16* __restrict__ out, int n4)
{
  for (int i = blockIdx.x * 256 + threadIdx.x; i < n4; i += gridDim.x * 256) {
    float4 v = *(const float4*)&in[4 * (size_t)i];
    ushort4 u = make_ushort4(f2bbits(v.x), f2bbits(v.y), f2bbits(v.z), f2bbits(v.w));
    *(ushort4*)&out[4 * (size_t)i] = u;
  }
}

// ---------------- prep: Wcat[n][k] = (k<512 ? lw[k][n] : rw[k-512][n]) as bf16 ----------------
__global__ __launch_bounds__(256) void wtrans_k(const float* __restrict__ lw,
                                                const float* __restrict__ rw,
                                                bf16* __restrict__ Wcat)
{
  __shared__ float s[32][33];
  const int tx = threadIdx.x & 31;
  const int ty = threadIdx.x >> 5;      // 0..7
  const int nt = blockIdx.x * 32;       // n tile
  const int kt = blockIdx.y * 32;       // k tile (0..1023)
#pragma unroll
  for (int q = 0; q < 4; ++q) {
    int k = kt + q * 8 + ty;
    int n = nt + tx;
    float v = (k < HD) ? lw[(size_t)k * HD + n] : rw[(size_t)(k - HD) * HD + n];
    s[q * 8 + ty][tx] = v;
  }
  __syncthreads();
#pragma unroll
  for (int q = 0; q < 4; ++q) {
    int n = nt + q * 8 + ty;
    int k = kt + tx;
    Wcat[(size_t)n * (2 * HD) + k] = __float2bfloat16(s[tx][q * 8 + ty]);
  }
}

// ---------------- CSR build ----------------
__global__ void count_k(const int* __restrict__ dst, int* __restrict__ cnt, int n)
{
  for (int i = blockIdx.x * blockDim.x + threadIdx.x; i < n; i += gridDim.x * blockDim.x)
    atomicAdd(&cnt[dst[i]], 1);
}

__global__ void scan_a(const int* __restrict__ in, int* __restrict__ out,
                       int* __restrict__ bsum, int n)
{
  __shared__ int s[256];
  const int tid = threadIdx.x;
  const int i = blockIdx.x * 256 + tid;
  int v = (i < n) ? in[i] : 0;
  s[tid] = v;
  __syncthreads();
  for (int d = 1; d < 256; d <<= 1) {
    int t = (tid >= d) ? s[tid - d] : 0;
    __syncthreads();
    s[tid] += t;
    __syncthreads();
  }
  if (i < n) out[i] = s[tid] - v;           // exclusive
  if (tid == 255) bsum[blockIdx.x] = s[255];
}

__global__ void scan_b(int* __restrict__ bsum, int nb)
{
  __shared__ int s[256];
  const int tid = threadIdx.x;
  int v = (tid < nb) ? bsum[tid] : 0;
  s[tid] = v;
  __syncthreads();
  for (int d = 1; d < 256; d <<= 1) {
    int t = (tid >= d) ? s[tid - d] : 0;
    __syncthreads();
    s[tid] += t;
    __syncthreads();
  }
  if (tid < nb) bsum[tid] = s[tid] - v;     // exclusive
}

__global__ void scan_c(int* __restrict__ out, const int* __restrict__ bsum, int n)
{
  const int i = blockIdx.x * 256 + threadIdx.x;
  if (i < n) out[i] += bsum[blockIdx.x];
}

__global__ void fill_k(const int* __restrict__ dst, const int* __restrict__ off,
                       int* __restrict__ fill, int* __restrict__ csr, int n)
{
  for (int i = blockIdx.x * blockDim.x + threadIdx.x; i < n; i += gridDim.x * blockDim.x) {
    int d = dst[i];
    int p = off[d] + atomicAdd(&fill[d], 1);
    csr[p] = i;
  }
}

// ---- folded classifier weights: Wl' = lw@cls, Wr' = rw@cls, cc = lb@cls ----
__global__ __launch_bounds__(64) void projw_k(
    const float* __restrict__ lw, const float* __restrict__ rw,
    const float* __restrict__ lb, const float* __restrict__ clsW,
    float* __restrict__ Wl, float* __restrict__ Wr, float* __restrict__ cc)
{
  const int k = blockIdx.x;
  const int l = threadIdx.x;
  if (k < HD) {
    float aL[NC] = {0, 0, 0, 0, 0, 0, 0};
    float aR[NC] = {0, 0, 0, 0, 0, 0, 0};
    for (int j = l; j < HD; j += 64) {
      float a = lw[(size_t)k * HD + j];
      float b = rw[(size_t)k * HD + j];
#pragma unroll
      for (int c = 0; c < NC; ++c) {
        float w = clsW[(size_t)j * NC + c];
        aL[c] += a * w;
        aR[c] += b * w;
      }
    }
#pragma unroll
    for (int c = 0; c < NC; ++c)
      for (int s = 32; s; s >>= 1) {
        aL[c] += __shfl_xor(aL[c], s);
        aR[c] += __shfl_xor(aR[c], s);
      }
    if (l == 0) {
#pragma unroll
      for (int c = 0; c < NC; ++c) {
        Wl[k * NC + c] = aL[c];
        Wr[k * NC + c] = aR[c];
      }
    }
  } else {
    float a0[NC] = {0, 0, 0, 0, 0, 0, 0};
    for (int j = l; j < HD; j += 64) {
      float a = lb[j];
#pragma unroll
      for (int c = 0; c < NC; ++c) a0[c] += a * clsW[(size_t)j * NC + c];
    }
#pragma unroll
    for (int c = 0; c < NC; ++c)
      for (int s = 32; s; s >>= 1) a0[c] += __shfl_xor(a0[c], s);
    if (l == 0) {
#pragma unroll
      for (int c = 0; c < NC; ++c) cc[c] = a0[c];
    }
  }
}

// ---- per-dst edge-attr sums: eaSum[d][0..6] (pad [7]=0), 8 lanes per dst ----
__global__ __launch_bounds__(256) void easum_k(
    const float* __restrict__ ea, const int* __restrict__ csr,
    const int* __restrict__ off, const int* __restrict__ cnt,
    float* __restrict__ eaSum, int ndst)
{
  const int g = threadIdx.x >> 3;
  const int cl = threadIdx.x & 7;
  const int d = blockIdx.x * 32 + g;
  if (d >= ndst) return;
  const int deg = cnt[d];
  const int start = off[d];
  float a = 0.f;
  for (int i = 0; i < deg; ++i) {
    int e = csr[start + i];
    if (cl < 7) a += ea[(size_t)e * EDIM + cl];
  }
  eaSum[(size_t)d * 8 + cl] = (cl < 7) ? a : 0.f;
}

// ---- tiny fold: ewP[j][c] = ew[j]@Wl[:,c], ebP[c] = eb@Wl[:,c]; 8 waves ----
__global__ __launch_bounds__(512) void proj2_k(
    const float* __restrict__ ew, const float* __restrict__ ebv,
    const float* __restrict__ Wl, float* __restrict__ ewP, float* __restrict__ ebP)
{
  const int j = threadIdx.x >> 6;   // 0..7 (7 == eb row)
  const int l = threadIdx.x & 63;
  const float* __restrict__ src = (j < 7) ? &ew[(size_t)j * HD] : ebv;
  float acc[NC] = {0, 0, 0, 0, 0, 0, 0};
  for (int k = l; k < HD; k += 64) {
    float v = src[k];
#pragma unroll
    for (int c = 0; c < NC; ++c) acc[c] += v * Wl[(size_t)k * NC + c];
  }
#pragma unroll
  for (int c = 0; c < NC; ++c)
    for (int s = 32; s; s >>= 1) acc[c] += __shfl_xor(acc[c], s);
  if (l == 0) {
    if (j < 7) {
#pragma unroll
      for (int c = 0; c < NC; ++c) ewP[j * 8 + c] = acc[c];
      ewP[j * 8 + 7] = 0.f;
    } else {
#pragma unroll
      for (int c = 0; c < NC; ++c) ebP[c] = acc[c];
      ebP[7] = 0.f;
    }
  }
}

// ---- dual row-projection: Pa = x@Wa, Pb = x@Wb  (x bf16 [rows,512]; out [rows,8] f32, pad=0)
__global__ __launch_bounds__(256) void dualproj_k(
    const bf16* __restrict__ x, const float* __restrict__ Wa,
    const float* __restrict__ Wb, float* __restrict__ Pa,
    float* __restrict__ Pb, int rows)
{
  __shared__ float Ws[2][HD][9];
  for (int idx = threadIdx.x; idx < HD * NC; idx += 256) {
    int k = idx / NC, c = idx - k * NC;
    Ws[0][k][c] = Wa[idx];
    Ws[1][k][c] = Wb[idx];
  }
  __syncthreads();
  const int lane = threadIdx.x & 63;
  const int w = threadIdx.x >> 6;
  for (int r = blockIdx.x * 4 + w; r < rows; r += gridDim.x * 4) {
    short8 xv = *(const short8*)&x[(size_t)r * HD + lane * 8];
    float xf[8];
#pragma unroll
    for (int j = 0; j < 8; ++j) xf[j] = b2f((unsigned short)xv[j]);
    float aA[NC] = {0, 0, 0, 0, 0, 0, 0};
    float aB[NC] = {0, 0, 0, 0, 0, 0, 0};
#pragma unroll
    for (int j = 0; j < 8; ++j) {
      const int k = lane * 8 + j;
#pragma unroll
      for (int c = 0; c < NC; ++c) {
        aA[c] += xf[j] * Ws[0][k][c];
        aB[c] += xf[j] * Ws[1][k][c];
      }
    }
#pragma unroll
    for (int c = 0; c < NC; ++c)
      for (int s = 32; s; s >>= 1) {
        aA[c] += __shfl_xor(aA[c], s);
        aB[c] += __shfl_xor(aB[c], s);
      }
    if (lane == 0) {
#pragma unroll
      for (int c = 0; c < NC; ++c) {
        Pa[(size_t)r * 8 + c] = aA[c];
        Pb[(size_t)r * 8 + c] = aB[c];
      }
      Pa[(size_t)r * 8 + 7] = 0.f;
      Pb[(size_t)r * 8 + 7] = 0.f;
    }
  }
}

// ---- layer-2 aggregation in projected (7-dim) space; 8 lanes per dst ----
__global__ __launch_bounds__(256) void agg_proj_k(
    const float* __restrict__ srcP, const float* __restrict__ ownP,
    const int* __restrict__ esrc, const int* __restrict__ csr,
    const int* __restrict__ off, const int* __restrict__ cnt,
    const float* __restrict__ eaSum, const float* __restrict__ ewP,
    const float* __restrict__ ebP, const float* __restrict__ cc,
    float* __restrict__ P, int ndst)
{
  const int g = threadIdx.x >> 3;
  const int cl = threadIdx.x & 7;
  const int d = blockIdx.x * 32 + g;
  if (d >= ndst) return;
  const int deg = cnt[d];
  const int start = off[d];
  float a = 0.f;
  int i = 0;
  for (; i + 1 < deg; i += 2) {
    int e0 = csr[start + i], e1 = csr[start + i + 1];
    int s0 = esrc[e0], s1 = esrc[e1];
    a += srcP[(size_t)s0 * 8 + cl] + srcP[(size_t)s1 * 8 + cl];
  }
  if (i < deg) {
    int e = csr[start + i];
    a += srcP[(size_t)esrc[e] * 8 + cl];
  }
  float r = ownP[(size_t)d * 8 + cl] + ((cl < 7) ? cc[cl] : 0.f);
  if (deg > 0) {
    float inv = 1.f / (float)deg;
    float es = 0.f;
#pragma unroll
    for (int j = 0; j < NC; ++j) es += eaSum[(size_t)d * 8 + j] * ewP[j * 8 + cl];
    r += (a + es) * inv + ebP[cl];
  }
  if (cl < 7) P[(size_t)d * NC + cl] = r;
}

// ---- layer-1 SpMM: wave per dst, 16B/lane gathers; epilogue uses eaSum ----
__global__ __launch_bounds__(256) void spmm_t(
    const bf16* __restrict__ xsrc, const int* __restrict__ esrc,
    const int* __restrict__ csr, const int* __restrict__ off,
    const int* __restrict__ cnt, const float* __restrict__ eaSum,
    const float* __restrict__ ew, const float* __restrict__ eb,
    bf16* __restrict__ t, int ndst)
{
  const int lane = threadIdx.x & 63;
  const int d = blockIdx.x * 4 + (threadIdx.x >> 6);
  if (d >= ndst) return;
  const int deg = cnt[d];
  const int start = off[d];
  const int c0 = lane * 8;
  float acc[8] = {0.f, 0.f, 0.f, 0.f, 0.f, 0.f, 0.f, 0.f};
  int i = 0;
  for (; i + 1 < deg; i += 2) {
    int e0 = csr[start + i], e1 = csr[start + i + 1];
    int s0 = esrc[e0], s1 = esrc[e1];
    short8 v0 = *(const short8*)&xsrc[(size_t)s0 * HD + c0];
    short8 v1 = *(const short8*)&xsrc[(size_t)s1 * HD + c0];
#pragma unroll
    for (int j = 0; j < 8; ++j)
      acc[j] += b2f((unsigned short)v0[j]) + b2f((unsigned short)v1[j]);
  }
  if (i < deg) {
    int e = csr[start + i];
    int s = esrc[e];
    short8 v = *(const short8*)&xsrc[(size_t)s * HD + c0];
#pragma unroll
    for (int j = 0; j < 8; ++j) acc[j] += b2f((unsigned short)v[j]);
  }
  short8 sv;
  if (deg > 0) {
    const float inv = 1.f / (float)deg;
    float es[8] = {0.f, 0.f, 0.f, 0.f, 0.f, 0.f, 0.f, 0.f};
#pragma unroll
    for (int j = 0; j < NC; ++j) {
      const float av = eaSum[(size_t)d * 8 + j];
      const float* __restrict__ wr = &ew[(size_t)j * HD + c0];
#pragma unroll
      for (int jj = 0; jj < 8; ++jj) es[jj] += av * wr[jj];
    }
#pragma unroll
    for (int jj = 0; jj < 8; ++jj)
      sv[jj] = (short)f2bbits((acc[jj] + es[jj]) * inv + eb[c0 + jj]);
  } else {
#pragma unroll
    for (int jj = 0; jj < 8; ++jj) sv[jj] = (short)f2bbits(0.f);
  }
  *(short8*)&t[(size_t)d * HD + c0] = sv;
}

// ---- MFMA GEMM (m97 structure): O = [A1|A2](bf16,[M,512] each) @ Wcat^T + bias, bf16 out
__global__ __launch_bounds__(256) void gemm_mfma(
    const bf16* __restrict__ A1, const bf16* __restrict__ A2,
    const bf16* __restrict__ Wcat, const float* __restrict__ bias,
    bf16* __restrict__ O, int M, int relu)
{
  __shared__ char lds[16384];       // A tile [128][32] bf16 @0, B tile [128][32] bf16 @8192
  const int tid = threadIdx.x;
  const int lane = tid & 63;
  const int wid = tid >> 6;
  const int wr = wid >> 1, wc = wid & 1;
  const int lr = lane & 15, lk = lane >> 4;
  const int m0 = blockIdx.x * 128;
  const int n0 = blockIdx.y * 128;

  const int srow = tid >> 2;        // 0..63
  const int sslot = tid & 3;

  f32x4 acc[4][4];
#pragma unroll
  for (int i = 0; i < 4; ++i)
#pragma unroll
    for (int j = 0; j < 4; ++j) acc[i][j] = (f32x4){0.f, 0.f, 0.f, 0.f};

  int gr0 = m0 + srow;       if (gr0 >= M) gr0 = M - 1;
  int gr1 = m0 + srow + 64;  if (gr1 >= M) gr1 = M - 1;
  const size_t aoff0 = (size_t)gr0 * HD + 8 * sslot;
  const size_t aoff1 = (size_t)gr1 * HD + 8 * sslot;
  const size_t boff0 = (size_t)(n0 + srow) * (2 * HD) + 8 * sslot;
  const size_t boff1 = (size_t)(n0 + srow + 64) * (2 * HD) + 8 * sslot;

  for (int ks = 0; ks < 32; ++ks) {
    const int k0 = ks * 32;
    const bf16* __restrict__ Ap = (k0 < HD) ? A1 : A2;
    const int ac = k0 & (HD - 1);
    gload16(Ap + aoff0 + ac, &lds[tid * 16]);
    gload16(Ap + aoff1 + ac, &lds[4096 + tid * 16]);
    gload16(Wcat + boff0 + k0, &lds[8192 + tid * 16]);
    gload16(Wcat + boff1 + k0, &lds[12288 + tid * 16]);
    __syncthreads();

    short8 af[4], bfr[4];
#pragma unroll
    for (int mf = 0; mf < 4; ++mf)
      af[mf] = *(const short8*)&lds[(wr * 64 + mf * 16 + lr) * 64 + lk * 16];
#pragma unroll
    for (int nf = 0; nf < 4; ++nf)
      bfr[nf] = *(const short8*)&lds[8192 + (wc * 64 + nf * 16 + lr) * 64 + lk * 16];
#pragma unroll
    for (int mf = 0; mf < 4; ++mf)
#pragma unroll
      for (int nf = 0; nf < 4; ++nf)
        acc[mf][nf] = __builtin_amdgcn_mfma_f32_16x16x32_bf16(
            af[mf], bfr[nf], acc[mf][nf], 0, 0, 0);
    __syncthreads();
  }

  const int colbase = n0 + wc * 64 + lr;
#pragma unroll
  for (int nf = 0; nf < 4; ++nf) {
    const int col = colbase + nf * 16;
    const float bv = bias[col];
#pragma unroll
    for (int mf = 0; mf < 4; ++mf) {
      const int rowb = m0 + wr * 64 + mf * 16 + lk * 4;
#pragma unroll
      for (int r = 0; r < 4; ++r) {
        const int row = rowb + r;
        if (row < M) {
          float v = acc[mf][nf][r] + bv;
          if (relu) v = fmaxf(v, 0.f);
          O[(size_t)row * HD + col] = __float2bfloat16(v);
        }
      }
    }
  }
}

__global__ void gather_out_k(const float* __restrict__ Pu, const float* __restrict__ Pm,
                             const int* __restrict__ eli, const float* __restrict__ cb,
                             float* __restrict__ out)
{
  const int i = blockIdx.x * 256 + threadIdx.x;
  if (i >= NEL * NC) return;
  int e = i / NC;
  int c = i - e * NC;
  out[i] = Pu[(size_t)eli[e] * NC + c] + Pm[(size_t)eli[NEL + e] * NC + c] + cb[c];
}

// ---------------- host side ----------------
static inline char* bump(char*& p, size_t bytes)
{
  char* r = p;
  p += (bytes + 255) & ~(size_t)255;
  return r;
}

extern "C" void kernel_launch(void* const* d_in, const int* in_sizes, int n_in,
                              void* d_out, int out_size, void* d_ws, size_t ws_size,
                              hipStream_t stream)
{
  const float* movie_x   = (const float*)d_in[0];
  const float* user_emb  = (const float*)d_in[1];
  const float* movie_emb = (const float*)d_in[2];
  const float* mlw       = (const float*)d_in[3];
  const float* mlb       = (const float*)d_in[4];
  const float* ea_um     = (const float*)d_in[5];
  const float* ea_mu     = (const float*)d_in[6];
  const float* mu1_lw = (const float*)d_in[7];
  const float* mu1_lb = (const float*)d_in[8];
  const float* mu1_rw = (const float*)d_in[9];
  const float* mu1_ew = (const float*)d_in[10];
  const float* mu1_eb = (const float*)d_in[11];
  const float* um1_lw = (const float*)d_in[12];
  const float* um1_lb = (const float*)d_in[13];
  const float* um1_rw = (const float*)d_in[14];
  const float* um1_ew = (const float*)d_in[15];
  const float* um1_eb = (const float*)d_in[16];
  const float* mu2_lw = (const float*)d_in[17];
  const float* mu2_lb = (const float*)d_in[18];
  const float* mu2_rw = (const float*)d_in[19];
  const float* mu2_ew = (const float*)d_in[20];
  const float* mu2_eb = (const float*)d_in[21];
  const float* um2_lw = (const float*)d_in[22];
  const float* um2_lb = (const float*)d_in[23];
  const float* um2_rw = (const float*)d_in[24];
  const float* um2_ew = (const float*)d_in[25];
  const float* um2_eb = (const float*)d_in[26];
  const float* cls_w  = (const float*)d_in[27];
  const float* cls_b  = (const float*)d_in[28];
  const int*   ei_um  = (const int*)d_in[29];   // [2, E]: src(user), dst(movie)
  const int*   ei_mu  = (const int*)d_in[30];   // [2, E]: src(movie), dst(user)
  const int*   eli    = (const int*)d_in[31];   // [2, EL]
  float* out = (float*)d_out;

  char* w = (char*)d_ws;
  bf16* x_m   = (bf16*)bump(w, (size_t)NMM * HD * 2);
  bf16* tbuf  = (bf16*)bump(w, (size_t)NUU * HD * 2);
  bf16* u1    = (bf16*)bump(w, (size_t)NUU * HD * 2);
  bf16* m1    = (bf16*)bump(w, (size_t)NMM * HD * 2);
  bf16* ue_bf = (bf16*)bump(w, (size_t)NUU * HD * 2);
  bf16* Wcat_u1 = (bf16*)bump(w, (size_t)HD * 2 * HD * 2);
  bf16* Wcat_m1 = (bf16*)bump(w, (size_t)HD * 2 * HD * 2);
  float* Pu   = (float*)bump(w, (size_t)NUU * NC * 4);
  float* Pm   = (float*)bump(w, (size_t)NMM * NC * 4);
  float* Wl_u = (float*)bump(w, (size_t)HD * NC * 4);
  float* Wr_u = (float*)bump(w, (size_t)HD * NC * 4);
  float* cc_u = (float*)bump(w, 64 * 4);
  float* Wl_m = (float*)bump(w, (size_t)HD * NC * 4);
  float* Wr_m = (float*)bump(w, (size_t)HD * NC * 4);
  float* cc_m = (float*)bump(w, 64 * 4);
  float* eaSum_u = (float*)bump(w, (size_t)NUU * 8 * 4);
  float* eaSum_m = (float*)bump(w, (size_t)NMM * 8 * 4);
  float* uP_l = (float*)bump(w, (size_t)NUU * 8 * 4);   // u1 @ Wl_m (src for movie-dst)
  float* uP_r = (float*)bump(w, (size_t)NUU * 8 * 4);   // u1 @ Wr_u (own for user-dst)
  float* mP_l = (float*)bump(w, (size_t)NMM * 8 * 4);   // m1 @ Wl_u (src for user-dst)
  float* mP_r = (float*)bump(w, (size_t)NMM * 8 * 4);   // m1 @ Wr_m (own for movie-dst)
  float* ewP_u = (float*)bump(w, 64 * 4);
  float* ebP_u = (float*)bump(w, 64 * 4);
  float* ewP_m = (float*)bump(w, 64 * 4);
  float* ebP_m = (float*)bump(w, 64 * 4);
  int* cf     = (int*)bump(w, (size_t)(2 * NUU + 2 * NMM) * 4);
  int* cnt_u  = cf;
  int* fill_u = cf + NUU;
  int* cnt_m  = cf + 2 * NUU;
  int* fill_m = cf + 2 * NUU + NMM;
  int* off_u  = (int*)bump(w, (size_t)NUU * 4);
  int* off_m  = (int*)bump(w, (size_t)NMM * 4);
  int* bsum   = (int*)bump(w, 256 * 4);
  int* csr_mu = (int*)bump(w, (size_t)NE * 4);
  int* csr_um = (int*)bump(w, (size_t)NE * 4);

  const int GU = (NUU + 255) / 256;   // 196
  const int GM = (NMM + 255) / 256;   // 79

  hipMemsetAsync(cf, 0, (size_t)(2 * NUU + 2 * NMM) * 4, stream);

  encoder_k<<<NMM, 256, 0, stream>>>(movie_x, mlw, mlb, movie_emb, x_m);
  cvt_bf16_k<<<2048, 256, 0, stream>>>(user_emb, ue_bf, NUU * HD / 4);
  {
    dim3 g(HD / 32, 2 * HD / 32);
    wtrans_k<<<g, 256, 0, stream>>>(mu1_lw, mu1_rw, Wcat_u1);
    wtrans_k<<<g, 256, 0, stream>>>(um1_lw, um1_rw, Wcat_m1);
  }

  count_k<<<1024, 256, 0, stream>>>(ei_mu + NE, cnt_u, NE);
  count_k<<<1024, 256, 0, stream>>>(ei_um + NE, cnt_m, NE);
  scan_a<<<GU, 256, 0, stream>>>(cnt_u, off_u, bsum, NUU);
  scan_b<<<1, 256, 0, stream>>>(bsum, GU);
  scan_c<<<GU, 256, 0, stream>>>(off_u, bsum, NUU);
  scan_a<<<GM, 256, 0, stream>>>(cnt_m, off_m, bsum, NMM);
  scan_b<<<1, 256, 0, stream>>>(bsum, GM);
  scan_c<<<GM, 256, 0, stream>>>(off_m, bsum, NMM);
  fill_k<<<1024, 256, 0, stream>>>(ei_mu + NE, off_u, fill_u, csr_mu, NE);
  fill_k<<<1024, 256, 0, stream>>>(ei_um + NE, off_m, fill_m, csr_um, NE);

  easum_k<<<(NUU + 31) / 32, 256, 0, stream>>>(ea_mu, csr_mu, off_u, cnt_u, eaSum_u, NUU);
  easum_k<<<(NMM + 31) / 32, 256, 0, stream>>>(ea_um, csr_um, off_m, cnt_m, eaSum_m, NMM);

  projw_k<<<HD + 1, 64, 0, stream>>>(mu2_lw, mu2_rw, mu2_lb, cls_w, Wl_u, Wr_u, cc_u);
  projw_k<<<HD + 1, 64, 0, stream>>>(um2_lw, um2_rw, um2_lb, cls_w + (size_t)HD * NC,
                                     Wl_m, Wr_m, cc_m);
  proj2_k<<<1, 512, 0, stream>>>(mu2_ew, mu2_eb, Wl_u, ewP_u, ebP_u);
  proj2_k<<<1, 512, 0, stream>>>(um2_ew, um2_eb, Wl_m, ewP_m, ebP_m);

  const dim3 gu((NUU + 127) / 128, HD / 128);   // 391 x 4
  const dim3 gm((NMM + 127) / 128, HD / 128);   // 157 x 4

  // layer 1: u1 = relu(conv(x_m -> users))
  spmm_t<<<(NUU + 3) / 4, 256, 0, stream>>>(x_m, ei_mu, csr_mu, off_u, cnt_u, eaSum_u,
                                            mu1_ew, mu1_eb, tbuf, NUU);
  gemm_mfma<<<gu, 256, 0, stream>>>(tbuf, ue_bf, Wcat_u1, mu1_lb, u1, NUU, 1);
  // layer 1: m1 = relu(conv(x_u -> movies))
  spmm_t<<<(NMM + 3) / 4, 256, 0, stream>>>(ue_bf, ei_um, csr_um, off_m, cnt_m, eaSum_m,
                                            um1_ew, um1_eb, tbuf, NMM);
  gemm_mfma<<<gm, 256, 0, stream>>>(tbuf, x_m, Wcat_m1, um1_lb, m1, NMM, 1);

  // layer 2 in projected 7-dim space
  dualproj_k<<<1024, 256, 0, stream>>>(u1, Wl_m, Wr_u, uP_l, uP_r, NUU);
  dualproj_k<<<1024, 256, 0, stream>>>(m1, Wl_u, Wr_m, mP_l, mP_r, NMM);
  agg_proj_k<<<(NUU + 31) / 32, 256, 0, stream>>>(mP_l, uP_r, ei_mu, csr_mu, off_u, cnt_u,
                                                  eaSum_u, ewP_u, ebP_u, cc_u, Pu, NUU);
  agg_proj_k<<<(NMM + 31) / 32, 256, 0, stream>>>(uP_l, mP_r, ei_um, csr_um, off_m, cnt_m,
                                                  eaSum_m, ewP_m, ebP_m, cc_m, Pm, NMM);

  gather_out_k<<<(NEL * NC + 255) / 256, 256, 0, stream>>>(Pu, Pm, eli, cls_b, out);
}

// Round 5
// 470.925 us; speedup vs baseline: 3.6015x; 1.3331x over previous
//
#include <hip/hip_runtime.h>
#include <hip/hip_bf16.h>

#define NUU 50000
#define NMM 20000
#define NT (NUU + NMM)
#define FEAT 32
#define NE 262144
#define NEL 100000
#define HD 512
#define EDIM 7
#define NC 7

typedef __hip_bfloat16 bf16;
typedef __attribute__((ext_vector_type(8))) short short8;
typedef __attribute__((ext_vector_type(4))) float f32x4;

__device__ __forceinline__ float b2f(unsigned short u)
{
  return __uint_as_float((unsigned)u << 16);
}
__device__ __forceinline__ unsigned short f2bbits(float x)
{
  __hip_bfloat16 h = __float2bfloat16(x);
  return *reinterpret_cast<unsigned short*>(&h);
}
__device__ __forceinline__ float2 ld2(const float* p) { return *(const float2*)p; }
__device__ __forceinline__ void st2b(bf16* p, float x, float y)
{
  ushort2 u = make_ushort2(f2bbits(x), f2bbits(y));
  *(ushort2*)p = u;
}
__device__ __forceinline__ void gload16(const void* g, void* l)
{
  __builtin_amdgcn_global_load_lds(
      (const __attribute__((address_space(1))) void*)g,
      (__attribute__((address_space(3))) void*)l, 16, 0, 0);
}

// ---------------- encoder: x_m = movie_x @ mlw + mlb + movie_emb (bf16 out) ----------------
__global__ __launch_bounds__(256) void encoder_k(
    const float* __restrict__ mx, const float* __restrict__ W,
    const float* __restrict__ b, const float* __restrict__ emb,
    bf16* __restrict__ xm)
{
  const int m = blockIdx.x;
  const int tid = threadIdx.x;
  const int c0 = 2 * tid;
  __shared__ float xr[FEAT];
  if (tid < FEAT) xr[tid] = mx[(size_t)m * FEAT + tid];
  __syncthreads();
  float2 e2 = ld2(&emb[(size_t)m * HD + c0]);
  float s0 = b[c0] + e2.x;
  float s1 = b[c0 + 1] + e2.y;
#pragma unroll
  for (int k = 0; k < FEAT; ++k) {
    float2 w2 = ld2(&W[(size_t)k * HD + c0]);
    s0 += xr[k] * w2.x;
    s1 += xr[k] * w2.y;
  }
  st2b(&xm[(size_t)m * HD + c0], s0, s1);
}

// ---------------- prep: fp32 -> bf16 copy ----------------
__global__ __launch_bounds__(256) void cvt_bf16_k(const float* __restrict__ in,
                                                  bf16* __restrict__ out, int n4)
{
  for (int i = blockIdx.x * 256 + threadIdx.x; i < n4; i += gridDim.x * 256) {
    float4 v = *(const float4*)&in[4 * (size_t)i];
    ushort4 u = make_ushort4(f2bbits(v.x), f2bbits(v.y), f2bbits(v.z), f2bbits(v.w));
    *(ushort4*)&out[4 * (size_t)i] = u;
  }
}

// ---------------- prep: Wcat[n][k] = (k<512 ? lw[k][n] : rw[k-512][n]) as bf16 ----------------
__global__ __launch_bounds__(256) void wtrans_k(const float* __restrict__ lw,
                                                const float* __restrict__ rw,
                                                bf16* __restrict__ Wcat)
{
  __shared__ float s[32][33];
  const int tx = threadIdx.x & 31;
  const int ty = threadIdx.x >> 5;      // 0..7
  const int nt = blockIdx.x * 32;       // n tile
  const int kt = blockIdx.y * 32;       // k tile (0..1023)
#pragma unroll
  for (int q = 0; q < 4; ++q) {
    int k = kt + q * 8 + ty;
    int n = nt + tx;
    float v = (k < HD) ? lw[(size_t)k * HD + n] : rw[(size_t)(k - HD) * HD + n];
    s[q * 8 + ty][tx] = v;
  }
  __syncthreads();
#pragma unroll
  for (int q = 0; q < 4; ++q) {
    int n = nt + q * 8 + ty;
    int k = kt + tx;
    Wcat[(size_t)n * (2 * HD) + k] = __float2bfloat16(s[tx][q * 8 + ty]);
  }
}

// ---------------- merged CSR build over concat'd [user | movie] dst space ----------------
__global__ void count2_k(const int* __restrict__ dmu, const int* __restrict__ dum,
                         int* __restrict__ cnt)
{
  for (int i = blockIdx.x * blockDim.x + threadIdx.x; i < NE; i += gridDim.x * blockDim.x) {
    atomicAdd(&cnt[dmu[i]], 1);
    atomicAdd(&cnt[NUU + dum[i]], 1);
  }
}

__global__ __launch_bounds__(512) void scan_a512(const int* __restrict__ in,
                                                 int* __restrict__ out,
                                                 int* __restrict__ bsum, int n)
{
  __shared__ int s[512];
  const int tid = threadIdx.x;
  const int i = blockIdx.x * 512 + tid;
  int v = (i < n) ? in[i] : 0;
  s[tid] = v;
  __syncthreads();
  for (int d = 1; d < 512; d <<= 1) {
    int t = (tid >= d) ? s[tid - d] : 0;
    __syncthreads();
    s[tid] += t;
    __syncthreads();
  }
  if (i < n) out[i] = s[tid] - v;           // exclusive
  if (tid == 511) bsum[blockIdx.x] = s[511];
}

__global__ void scan_b256(int* __restrict__ bsum, int nb)
{
  __shared__ int s[256];
  const int tid = threadIdx.x;
  int v = (tid < nb) ? bsum[tid] : 0;
  s[tid] = v;
  __syncthreads();
  for (int d = 1; d < 256; d <<= 1) {
    int t = (tid >= d) ? s[tid - d] : 0;
    __syncthreads();
    s[tid] += t;
    __syncthreads();
  }
  if (tid < nb) bsum[tid] = s[tid] - v;     // exclusive
}

__global__ __launch_bounds__(512) void scan_c512(int* __restrict__ out,
                                                 const int* __restrict__ bsum, int n)
{
  const int i = blockIdx.x * 512 + threadIdx.x;
  if (i < n) out[i] += bsum[blockIdx.x];
}

__global__ void fill2_k(const int* __restrict__ dmu, const int* __restrict__ dum,
                        const int* __restrict__ off, int* __restrict__ fill,
                        int* __restrict__ csr)
{
  for (int i = blockIdx.x * blockDim.x + threadIdx.x; i < NE; i += gridDim.x * blockDim.x) {
    int d0 = dmu[i];
    int p0 = off[d0] + atomicAdd(&fill[d0], 1);
    csr[p0] = i;
    int d1 = NUU + dum[i];
    int p1 = off[d1] + atomicAdd(&fill[d1], 1);
    csr[p1] = i;
  }
}

// ---- per-dst edge-attr sums over concat dst space: eaSum[d][0..6], pad [7]=0 ----
__global__ __launch_bounds__(256) void easum2_k(
    const float* __restrict__ eaMU, const float* __restrict__ eaUM,
    const int* __restrict__ csr, const int* __restrict__ off,
    const int* __restrict__ cnt, float* __restrict__ eaSum)
{
  const int g = threadIdx.x >> 3;
  const int cl = threadIdx.x & 7;
  const int d = blockIdx.x * 32 + g;
  if (d >= NT) return;
  const float* __restrict__ ea = (d < NUU) ? eaMU : eaUM;
  const int deg = cnt[d];
  const int start = off[d];
  float a = 0.f;
  for (int i = 0; i < deg; ++i) {
    int e = csr[start + i];
    if (cl < 7) a += ea[(size_t)e * EDIM + cl];
  }
  eaSum[(size_t)d * 8 + cl] = (cl < 7) ? a : 0.f;
}

// ---- folded classifier weights: Wl' = lw@cls, Wr' = rw@cls, cc = lb@cls ----
__global__ __launch_bounds__(64) void projw_k(
    const float* __restrict__ lw, const float* __restrict__ rw,
    const float* __restrict__ lb, const float* __restrict__ clsW,
    float* __restrict__ Wl, float* __restrict__ Wr, float* __restrict__ cc)
{
  const int k = blockIdx.x;
  const int l = threadIdx.x;
  if (k < HD) {
    float aL[NC] = {0, 0, 0, 0, 0, 0, 0};
    float aR[NC] = {0, 0, 0, 0, 0, 0, 0};
    for (int j = l; j < HD; j += 64) {
      float a = lw[(size_t)k * HD + j];
      float b = rw[(size_t)k * HD + j];
#pragma unroll
      for (int c = 0; c < NC; ++c) {
        float w = clsW[(size_t)j * NC + c];
        aL[c] += a * w;
        aR[c] += b * w;
      }
    }
#pragma unroll
    for (int c = 0; c < NC; ++c)
      for (int s = 32; s; s >>= 1) {
        aL[c] += __shfl_xor(aL[c], s);
        aR[c] += __shfl_xor(aR[c], s);
      }
    if (l == 0) {
#pragma unroll
      for (int c = 0; c < NC; ++c) {
        Wl[k * NC + c] = aL[c];
        Wr[k * NC + c] = aR[c];
      }
    }
  } else {
    float a0[NC] = {0, 0, 0, 0, 0, 0, 0};
    for (int j = l; j < HD; j += 64) {
      float a = lb[j];
#pragma unroll
      for (int c = 0; c < NC; ++c) a0[c] += a * clsW[(size_t)j * NC + c];
    }
#pragma unroll
    for (int c = 0; c < NC; ++c)
      for (int s = 32; s; s >>= 1) a0[c] += __shfl_xor(a0[c], s);
    if (l == 0) {
#pragma unroll
      for (int c = 0; c < NC; ++c) cc[c] = a0[c];
    }
  }
}

// ---- tiny fold: ewP[j][c] = ew[j]@Wl[:,c], ebP[c] = eb@Wl[:,c]; 8 waves ----
__global__ __launch_bounds__(512) void proj2_k(
    const float* __restrict__ ew, const float* __restrict__ ebv,
    const float* __restrict__ Wl, float* __restrict__ ewP, float* __restrict__ ebP)
{
  const int j = threadIdx.x >> 6;   // 0..7 (7 == eb row)
  const int l = threadIdx.x & 63;
  const float* __restrict__ src = (j < 7) ? &ew[(size_t)j * HD] : ebv;
  float acc[NC] = {0, 0, 0, 0, 0, 0, 0};
  for (int k = l; k < HD; k += 64) {
    float v = src[k];
#pragma unroll
    for (int c = 0; c < NC; ++c) acc[c] += v * Wl[(size_t)k * NC + c];
  }
#pragma unroll
  for (int c = 0; c < NC; ++c)
    for (int s = 32; s; s >>= 1) acc[c] += __shfl_xor(acc[c], s);
  if (l == 0) {
    if (j < 7) {
#pragma unroll
      for (int c = 0; c < NC; ++c) ewP[j * 8 + c] = acc[c];
      ewP[j * 8 + 7] = 0.f;
    } else {
#pragma unroll
      for (int c = 0; c < NC; ++c) ebP[c] = acc[c];
      ebP[7] = 0.f;
    }
  }
}

// ---- prep: W2t[16][512] bf16: rows 0..6 = WA^T, 7 = 0, 8..14 = WB^T, 15 = 0 ----
__global__ __launch_bounds__(256) void w2t_k(const float* __restrict__ WA,
                                             const float* __restrict__ WB,
                                             bf16* __restrict__ W2t)
{
  int idx = blockIdx.x * 256 + threadIdx.x;
  if (idx >= 16 * HD) return;
  int n = idx >> 9;
  int k = idx & (HD - 1);
  float v = 0.f;
  if (n < 7) v = WA[k * NC + n];
  else if (n >= 8 && n < 15) v = WB[k * NC + (n - 8)];
  W2t[(size_t)n * HD + k] = __float2bfloat16(v);
}

// ---- layer-2 aggregation in projected (7-dim) space; 8 lanes per dst ----
__global__ __launch_bounds__(256) void agg_proj_k(
    const float* __restrict__ srcP, const float* __restrict__ ownP,
    const int* __restrict__ esrc, const int* __restrict__ csr,
    const int* __restrict__ off, const int* __restrict__ cnt,
    const float* __restrict__ eaSum, const float* __restrict__ ewP,
    const float* __restrict__ ebP, const float* __restrict__ cc,
    float* __restrict__ P, int ndst)
{
  const int g = threadIdx.x >> 3;
  const int cl = threadIdx.x & 7;
  const int d = blockIdx.x * 32 + g;
  if (d >= ndst) return;
  const int deg = cnt[d];
  const int start = off[d];
  float a = 0.f;
  int i = 0;
  for (; i + 1 < deg; i += 2) {
    int e0 = csr[start + i], e1 = csr[start + i + 1];
    int s0 = esrc[e0], s1 = esrc[e1];
    a += srcP[(size_t)s0 * 8 + cl] + srcP[(size_t)s1 * 8 + cl];
  }
  if (i < deg) {
    int e = csr[start + i];
    a += srcP[(size_t)esrc[e] * 8 + cl];
  }
  float r = ownP[(size_t)d * 8 + cl] + ((cl < 7) ? cc[cl] : 0.f);
  if (deg > 0) {
    float inv = 1.f / (float)deg;
    float es = 0.f;
#pragma unroll
    for (int j = 0; j < NC; ++j) es += eaSum[(size_t)d * 8 + j] * ewP[j * 8 + cl];
    r += (a + es) * inv + ebP[cl];
  }
  if (cl < 7) P[(size_t)d * NC + cl] = r;
}

// ---- layer-1 SpMM: wave per dst, 16B/lane gathers, unroll-4; epilogue uses eaSum ----
__global__ __launch_bounds__(256) void spmm_t(
    const bf16* __restrict__ xsrc, const int* __restrict__ esrc,
    const int* __restrict__ csr, const int* __restrict__ off,
    const int* __restrict__ cnt, const float* __restrict__ eaSum,
    const float* __restrict__ ew, const float* __restrict__ eb,
    bf16* __restrict__ t, int ndst)
{
  const int lane = threadIdx.x & 63;
  const int d = blockIdx.x * 4 + (threadIdx.x >> 6);
  if (d >= ndst) return;
  const int deg = cnt[d];
  const int start = off[d];
  const int c0 = lane * 8;
  float acc[8] = {0.f, 0.f, 0.f, 0.f, 0.f, 0.f, 0.f, 0.f};
  int i = 0;
  for (; i + 3 < deg; i += 4) {
    int e0 = csr[start + i], e1 = csr[start + i + 1];
    int e2 = csr[start + i + 2], e3 = csr[start + i + 3];
    int s0 = esrc[e0], s1 = esrc[e1], s2 = esrc[e2], s3 = esrc[e3];
    short8 v0 = *(const short8*)&xsrc[(size_t)s0 * HD + c0];
    short8 v1 = *(const short8*)&xsrc[(size_t)s1 * HD + c0];
    short8 v2 = *(const short8*)&xsrc[(size_t)s2 * HD + c0];
    short8 v3 = *(const short8*)&xsrc[(size_t)s3 * HD + c0];
#pragma unroll
    for (int j = 0; j < 8; ++j)
      acc[j] += (b2f((unsigned short)v0[j]) + b2f((unsigned short)v1[j])) +
                (b2f((unsigned short)v2[j]) + b2f((unsigned short)v3[j]));
  }
  for (; i < deg; ++i) {
    int e = csr[start + i];
    int s = esrc[e];
    short8 v = *(const short8*)&xsrc[(size_t)s * HD + c0];
#pragma unroll
    for (int j = 0; j < 8; ++j) acc[j] += b2f((unsigned short)v[j]);
  }
  short8 sv;
  if (deg > 0) {
    const float inv = 1.f / (float)deg;
    float es[8] = {0.f, 0.f, 0.f, 0.f, 0.f, 0.f, 0.f, 0.f};
#pragma unroll
    for (int j = 0; j < NC; ++j) {
      const float av = eaSum[(size_t)d * 8 + j];
      const float* __restrict__ wr = &ew[(size_t)j * HD + c0];
#pragma unroll
      for (int jj = 0; jj < 8; ++jj) es[jj] += av * wr[jj];
    }
#pragma unroll
    for (int jj = 0; jj < 8; ++jj)
      sv[jj] = (short)f2bbits((acc[jj] + es[jj]) * inv + eb[c0 + jj]);
  } else {
#pragma unroll
    for (int jj = 0; jj < 8; ++jj) sv[jj] = (short)f2bbits(0.f);
  }
  *(short8*)&t[(size_t)d * HD + c0] = sv;
}

// ---- MFMA GEMM + fused dual 7-dim projection epilogue.
// z = [A1|A2] @ Wcat^T + bias; relu; Ppart[nt][row][16] += relu(z_blockcols) @ W2t^T.
// u1/m1 never materialized. Tile 128x128, BK=32, 4 waves, XCD-bijective swizzle.
__global__ __launch_bounds__(256) void gemm_mfma(
    const bf16* __restrict__ A1, const bf16* __restrict__ A2,
    const bf16* __restrict__ Wcat, const float* __restrict__ bias,
    const bf16* __restrict__ W2t, float* __restrict__ Ppart, int M)
{
  __shared__ __align__(16) char lds[34816];   // staging 16KB; epilogue z[128][136] bf16
  const int tid = threadIdx.x;
  const int lane = tid & 63;
  const int wid = tid >> 6;
  const int wr = wid >> 1, wc = wid & 1;
  const int lr = lane & 15, lk = lane >> 4;

  // XCD-bijective swizzle (m204), n-fastest decode
  const int nwg = gridDim.x;
  const int orig = blockIdx.x;
  const int q = nwg >> 3, r8 = nwg & 7;
  const int xcd = orig & 7, pos = orig >> 3;
  const int wg = (xcd < r8) ? xcd * (q + 1) + pos : r8 * (q + 1) + (xcd - r8) * q + pos;
  const int mt = wg >> 2, nt = wg & 3;
  const int m0 = mt * 128;
  const int n0 = nt * 128;

  const int srow = tid >> 2;        // 0..63
  const int sslot = tid & 3;

  f32x4 acc[4][4];
#pragma unroll
  for (int i = 0; i < 4; ++i)
#pragma unroll
    for (int j = 0; j < 4; ++j) acc[i][j] = (f32x4){0.f, 0.f, 0.f, 0.f};

  int gr0 = m0 + srow;       if (gr0 >= M) gr0 = M - 1;
  int gr1 = m0 + srow + 64;  if (gr1 >= M) gr1 = M - 1;
  const size_t aoff0 = (size_t)gr0 * HD + 8 * sslot;
  const size_t aoff1 = (size_t)gr1 * HD + 8 * sslot;
  const size_t boff0 = (size_t)(n0 + srow) * (2 * HD) + 8 * sslot;
  const size_t boff1 = (size_t)(n0 + srow + 64) * (2 * HD) + 8 * sslot;

  for (int ks = 0; ks < 32; ++ks) {
    const int k0 = ks * 32;
    const bf16* __restrict__ Ap = (k0 < HD) ? A1 : A2;
    const int ac = k0 & (HD - 1);
    gload16(Ap + aoff0 + ac, &lds[tid * 16]);
    gload16(Ap + aoff1 + ac, &lds[4096 + tid * 16]);
    gload16(Wcat + boff0 + k0, &lds[8192 + tid * 16]);
    gload16(Wcat + boff1 + k0, &lds[12288 + tid * 16]);
    __syncthreads();

    short8 af[4], bfr[4];
#pragma unroll
    for (int mf = 0; mf < 4; ++mf)
      af[mf] = *(const short8*)&lds[(wr * 64 + mf * 16 + lr) * 64 + lk * 16];
#pragma unroll
    for (int nf = 0; nf < 4; ++nf)
      bfr[nf] = *(const short8*)&lds[8192 + (wc * 64 + nf * 16 + lr) * 64 + lk * 16];
#pragma unroll
    for (int mf = 0; mf < 4; ++mf)
#pragma unroll
      for (int nf = 0; nf < 4; ++nf)
        acc[mf][nf] = __builtin_amdgcn_mfma_f32_16x16x32_bf16(
            af[mf], bfr[nf], acc[mf][nf], 0, 0, 0);
    __syncthreads();
  }

  // ---- epilogue: relu(z) -> LDS tile [128][136] bf16 ----
  bf16* zs = (bf16*)lds;
  const int ZLD = 136;
#pragma unroll
  for (int nf = 0; nf < 4; ++nf) {
    const int col_l = wc * 64 + nf * 16 + lr;
    const float bv = bias[n0 + col_l];
#pragma unroll
    for (int mf = 0; mf < 4; ++mf) {
      const int row_l = wr * 64 + mf * 16 + lk * 4;
#pragma unroll
      for (int r = 0; r < 4; ++r) {
        float v = fmaxf(acc[mf][nf][r] + bv, 0.f);
        zs[(size_t)(row_l + r) * ZLD + col_l] = __float2bfloat16(v);
      }
    }
  }
  __syncthreads();

  // ---- per-wave 32-row strip: Ppart[nt][row][0..15] = z_strip @ W2t^T ----
  const int strip = wid * 32;
  f32x4 p0 = {0.f, 0.f, 0.f, 0.f}, p1 = {0.f, 0.f, 0.f, 0.f};
#pragma unroll
  for (int kk = 0; kk < 4; ++kk) {
    short8 bfg = *(const short8*)&W2t[(size_t)lr * HD + n0 + kk * 32 + 8 * lk];
    short8 a0 = *(const short8*)&zs[(size_t)(strip + lr) * ZLD + kk * 32 + 8 * lk];
    short8 a1 = *(const short8*)&zs[(size_t)(strip + 16 + lr) * ZLD + kk * 32 + 8 * lk];
    p0 = __builtin_amdgcn_mfma_f32_16x16x32_bf16(a0, bfg, p0, 0, 0, 0);
    p1 = __builtin_amdgcn_mfma_f32_16x16x32_bf16(a1, bfg, p1, 0, 0, 0);
  }
#pragma unroll
  for (int r = 0; r < 4; ++r) {
    int row0 = m0 + strip + lk * 4 + r;
    if (row0 < M) Ppart[((size_t)nt * M + row0) * 16 + lr] = p0[r];
    int row1 = m0 + strip + 16 + lk * 4 + r;
    if (row1 < M) Ppart[((size_t)nt * M + row1) * 16 + lr] = p1[r];
  }
}

// ---- sum 4 n-tile partials, split into Pa[rows][8], Pb[rows][8] ----
__global__ __launch_bounds__(256) void reduce4_k(
    const float* __restrict__ PpU, const float* __restrict__ PpM,
    float* __restrict__ uPa, float* __restrict__ uPb,
    float* __restrict__ mPa, float* __restrict__ mPb)
{
  int idx = blockIdx.x * 256 + threadIdx.x;
  if (idx >= NT * 16) return;
  int row = idx >> 4, j = idx & 15;
  const float* Pp;
  float *Pa, *Pb;
  int rows, r;
  if (row < NUU) { Pp = PpU; Pa = uPa; Pb = uPb; rows = NUU; r = row; }
  else { Pp = PpM; Pa = mPa; Pb = mPb; rows = NMM; r = row - NUU; }
  float s = Pp[((size_t)0 * rows + r) * 16 + j] + Pp[((size_t)1 * rows + r) * 16 + j] +
            Pp[((size_t)2 * rows + r) * 16 + j] + Pp[((size_t)3 * rows + r) * 16 + j];
  if (j < 8) Pa[(size_t)r * 8 + j] = s;
  else Pb[(size_t)r * 8 + (j - 8)] = s;
}

__global__ void gather_out_k(const float* __restrict__ Pu, const float* __restrict__ Pm,
                             const int* __restrict__ eli, const float* __restrict__ cb,
                             float* __restrict__ out)
{
  const int i = blockIdx.x * 256 + threadIdx.x;
  if (i >= NEL * NC) return;
  int e = i / NC;
  int c = i - e * NC;
  out[i] = Pu[(size_t)eli[e] * NC + c] + Pm[(size_t)eli[NEL + e] * NC + c] + cb[c];
}

// ---------------- host side ----------------
static inline char* bump(char*& p, size_t bytes)
{
  char* r = p;
  p += (bytes + 255) & ~(size_t)255;
  return r;
}

extern "C" void kernel_launch(void* const* d_in, const int* in_sizes, int n_in,
                              void* d_out, int out_size, void* d_ws, size_t ws_size,
                              hipStream_t stream)
{
  const float* movie_x   = (const float*)d_in[0];
  const float* user_emb  = (const float*)d_in[1];
  const float* movie_emb = (const float*)d_in[2];
  const float* mlw       = (const float*)d_in[3];
  const float* mlb       = (const float*)d_in[4];
  const float* ea_um     = (const float*)d_in[5];
  const float* ea_mu     = (const float*)d_in[6];
  const float* mu1_lw = (const float*)d_in[7];
  const float* mu1_lb = (const float*)d_in[8];
  const float* mu1_rw = (const float*)d_in[9];
  const float* mu1_ew = (const float*)d_in[10];
  const float* mu1_eb = (const float*)d_in[11];
  const float* um1_lw = (const float*)d_in[12];
  const float* um1_lb = (const float*)d_in[13];
  const float* um1_rw = (const float*)d_in[14];
  const float* um1_ew = (const float*)d_in[15];
  const float* um1_eb = (const float*)d_in[16];
  const float* mu2_lw = (const float*)d_in[17];
  const float* mu2_lb = (const float*)d_in[18];
  const float* mu2_rw = (const float*)d_in[19];
  const float* mu2_ew = (const float*)d_in[20];
  const float* mu2_eb = (const float*)d_in[21];
  const float* um2_lw = (const float*)d_in[22];
  const float* um2_lb = (const float*)d_in[23];
  const float* um2_rw = (const float*)d_in[24];
  const float* um2_ew = (const float*)d_in[25];
  const float* um2_eb = (const float*)d_in[26];
  const float* cls_w  = (const float*)d_in[27];
  const float* cls_b  = (const float*)d_in[28];
  const int*   ei_um  = (const int*)d_in[29];   // [2, E]: src(user), dst(movie)
  const int*   ei_mu  = (const int*)d_in[30];   // [2, E]: src(movie), dst(user)
  const int*   eli    = (const int*)d_in[31];   // [2, EL]
  float* out = (float*)d_out;

  char* w = (char*)d_ws;
  bf16* x_m   = (bf16*)bump(w, (size_t)NMM * HD * 2);
  bf16* tbuf  = (bf16*)bump(w, (size_t)NUU * HD * 2);
  bf16* ue_bf = (bf16*)bump(w, (size_t)NUU * HD * 2);
  bf16* Wcat_u1 = (bf16*)bump(w, (size_t)HD * 2 * HD * 2);
  bf16* Wcat_m1 = (bf16*)bump(w, (size_t)HD * 2 * HD * 2);
  float* PpU  = (float*)bump(w, (size_t)4 * NUU * 16 * 4);
  float* PpM  = (float*)bump(w, (size_t)4 * NMM * 16 * 4);
  float* uPa  = (float*)bump(w, (size_t)NUU * 8 * 4);   // u1 @ Wl_m (src for movie-dst)
  float* uPb  = (float*)bump(w, (size_t)NUU * 8 * 4);   // u1 @ Wr_u (own for user-dst)
  float* mPa  = (float*)bump(w, (size_t)NMM * 8 * 4);   // m1 @ Wl_u (src for user-dst)
  float* mPb  = (float*)bump(w, (size_t)NMM * 8 * 4);   // m1 @ Wr_m (own for movie-dst)
  float* Pu   = (float*)bump(w, (size_t)NUU * NC * 4);
  float* Pm   = (float*)bump(w, (size_t)NMM * NC * 4);
  float* Wl_u = (float*)bump(w, (size_t)HD * NC * 4);
  float* Wr_u = (float*)bump(w, (size_t)HD * NC * 4);
  float* cc_u = (float*)bump(w, 64 * 4);
  float* Wl_m = (float*)bump(w, (size_t)HD * NC * 4);
  float* Wr_m = (float*)bump(w, (size_t)HD * NC * 4);
  float* cc_m = (float*)bump(w, 64 * 4);
  bf16* W2t_u = (bf16*)bump(w, (size_t)16 * HD * 2);
  bf16* W2t_m = (bf16*)bump(w, (size_t)16 * HD * 2);
  float* eaSum = (float*)bump(w, (size_t)NT * 8 * 4);
  float* ewP_u = (float*)bump(w, 64 * 4);
  float* ebP_u = (float*)bump(w, 64 * 4);
  float* ewP_m = (float*)bump(w, 64 * 4);
  float* ebP_m = (float*)bump(w, 64 * 4);
  int* cf     = (int*)bump(w, (size_t)2 * NT * 4);   // cnt | fill
  int* cnt    = cf;
  int* fill   = cf + NT;
  int* off    = (int*)bump(w, (size_t)NT * 4);
  int* bsum   = (int*)bump(w, 256 * 4);
  int* csr    = (int*)bump(w, (size_t)2 * NE * 4);

  const int GN = (NT + 511) / 512;    // 137 scan blocks

  hipMemsetAsync(cf, 0, (size_t)2 * NT * 4, stream);

  encoder_k<<<NMM, 256, 0, stream>>>(movie_x, mlw, mlb, movie_emb, x_m);
  cvt_bf16_k<<<2048, 256, 0, stream>>>(user_emb, ue_bf, NUU * HD / 4);
  {
    dim3 g(HD / 32, 2 * HD / 32);
    wtrans_k<<<g, 256, 0, stream>>>(mu1_lw, mu1_rw, Wcat_u1);
    wtrans_k<<<g, 256, 0, stream>>>(um1_lw, um1_rw, Wcat_m1);
  }

  count2_k<<<1024, 256, 0, stream>>>(ei_mu + NE, ei_um + NE, cnt);
  scan_a512<<<GN, 512, 0, stream>>>(cnt, off, bsum, NT);
  scan_b256<<<1, 256, 0, stream>>>(bsum, GN);
  scan_c512<<<GN, 512, 0, stream>>>(off, bsum, NT);
  fill2_k<<<1024, 256, 0, stream>>>(ei_mu + NE, ei_um + NE, off, fill, csr);
  easum2_k<<<(NT + 31) / 32, 256, 0, stream>>>(ea_mu, ea_um, csr, off, cnt, eaSum);

  projw_k<<<HD + 1, 64, 0, stream>>>(mu2_lw, mu2_rw, mu2_lb, cls_w, Wl_u, Wr_u, cc_u);
  projw_k<<<HD + 1, 64, 0, stream>>>(um2_lw, um2_rw, um2_lb, cls_w + (size_t)HD * NC,
                                     Wl_m, Wr_m, cc_m);
  proj2_k<<<1, 512, 0, stream>>>(mu2_ew, mu2_eb, Wl_u, ewP_u, ebP_u);
  proj2_k<<<1, 512, 0, stream>>>(um2_ew, um2_eb, Wl_m, ewP_m, ebP_m);
  w2t_k<<<32, 256, 0, stream>>>(Wl_m, Wr_u, W2t_u);   // user gemm: A=Wl_m, B=Wr_u
  w2t_k<<<32, 256, 0, stream>>>(Wl_u, Wr_m, W2t_m);   // movie gemm: A=Wl_u, B=Wr_m

  const int nwgU = ((NUU + 127) / 128) * 4;   // 1564
  const int nwgM = ((NMM + 127) / 128) * 4;   // 628

  // layer 1 + fused layer-2 projections
  spmm_t<<<(NUU + 3) / 4, 256, 0, stream>>>(x_m, ei_mu, csr, off, cnt, eaSum,
                                            mu1_ew, mu1_eb, tbuf, NUU);
  gemm_mfma<<<nwgU, 256, 0, stream>>>(tbuf, ue_bf, Wcat_u1, mu1_lb, W2t_u, PpU, NUU);
  spmm_t<<<(NMM + 3) / 4, 256, 0, stream>>>(ue_bf, ei_um, csr, off + NUU, cnt + NUU,
                                            eaSum + (size_t)NUU * 8,
                                            um1_ew, um1_eb, tbuf, NMM);
  gemm_mfma<<<nwgM, 256, 0, stream>>>(tbuf, x_m, Wcat_m1, um1_lb, W2t_m, PpM, NMM);

  reduce4_k<<<(NT * 16 + 255) / 256, 256, 0, stream>>>(PpU, PpM, uPa, uPb, mPa, mPb);

  // layer-2 aggregation in 7-dim space
  agg_proj_k<<<(NUU + 31) / 32, 256, 0, stream>>>(mPa, uPb, ei_mu, csr, off, cnt,
                                                  eaSum, ewP_u, ebP_u, cc_u, Pu, NUU);
  agg_proj_k<<<(NMM + 31) / 32, 256, 0, stream>>>(uPa, mPb, ei_um, csr, off + NUU,
                                                  cnt + NUU, eaSum + (size_t)NUU * 8,
                                                  ewP_m, ebP_m, cc_m, Pm, NMM);

  gather_out_k<<<(NEL * NC + 255) / 256, 256, 0, stream>>>(Pu, Pm, eli, cls_b, out);
}

// Round 6
// 420.103 us; speedup vs baseline: 4.0372x; 1.1210x over previous
//
#include <hip/hip_runtime.h>
#include <hip/hip_bf16.h>

#define NUU 50000
#define NMM 20000
#define NT (NUU + NMM)
#define FEAT 32
#define NE 262144
#define NEL 100000
#define HD 512
#define EDIM 7
#define NC 7

typedef __hip_bfloat16 bf16;
typedef __attribute__((ext_vector_type(8))) short short8;
typedef __attribute__((ext_vector_type(4))) float f32x4;

__device__ __forceinline__ float b2f(unsigned short u)
{
  return __uint_as_float((unsigned)u << 16);
}
__device__ __forceinline__ unsigned short f2bbits(float x)
{
  __hip_bfloat16 h = __float2bfloat16(x);
  return *reinterpret_cast<unsigned short*>(&h);
}
__device__ __forceinline__ float2 ld2(const float* p) { return *(const float2*)p; }
__device__ __forceinline__ void st2b(bf16* p, float x, float y)
{
  ushort2 u = make_ushort2(f2bbits(x), f2bbits(y));
  *(ushort2*)p = u;
}
__device__ __forceinline__ void gload16(const void* g, void* l)
{
  __builtin_amdgcn_global_load_lds(
      (const __attribute__((address_space(1))) void*)g,
      (__attribute__((address_space(3))) void*)l, 16, 0, 0);
}

// ---------------- encoder: x_m = movie_x @ mlw + mlb + movie_emb (bf16 out) ----------------
// Grid-stride; W slice cached in registers (64 VGPR), loaded once per block.
__global__ __launch_bounds__(256) void encoder_k(
    const float* __restrict__ mx, const float* __restrict__ W,
    const float* __restrict__ b, const float* __restrict__ emb,
    bf16* __restrict__ xm)
{
  const int tid = threadIdx.x;
  const int c0 = 2 * tid;
  float2 wreg[FEAT];
#pragma unroll
  for (int k = 0; k < FEAT; ++k) wreg[k] = ld2(&W[(size_t)k * HD + c0]);
  const float2 bv = ld2(&b[c0]);
  __shared__ float xr[FEAT];
  for (int m = blockIdx.x; m < NMM; m += gridDim.x) {
    if (tid < FEAT) xr[tid] = mx[(size_t)m * FEAT + tid];
    __syncthreads();
    float2 e2 = ld2(&emb[(size_t)m * HD + c0]);
    float s0 = bv.x + e2.x, s1 = bv.y + e2.y;
#pragma unroll
    for (int k = 0; k < FEAT; ++k) {
      s0 += xr[k] * wreg[k].x;
      s1 += xr[k] * wreg[k].y;
    }
    st2b(&xm[(size_t)m * HD + c0], s0, s1);
    __syncthreads();
  }
}

// ---------------- prep: fp32 -> bf16 copy ----------------
__global__ __launch_bounds__(256) void cvt_bf16_k(const float* __restrict__ in,
                                                  bf16* __restrict__ out, int n4)
{
  for (int i = blockIdx.x * 256 + threadIdx.x; i < n4; i += gridDim.x * 256) {
    float4 v = *(const float4*)&in[4 * (size_t)i];
    ushort4 u = make_ushort4(f2bbits(v.x), f2bbits(v.y), f2bbits(v.z), f2bbits(v.w));
    *(ushort4*)&out[4 * (size_t)i] = u;
  }
}

// ---------------- prep: Wcat[n][k] = (k<512 ? lw[k][n] : rw[k-512][n]) as bf16 ----------------
__global__ __launch_bounds__(256) void wtrans_k(const float* __restrict__ lw,
                                                const float* __restrict__ rw,
                                                bf16* __restrict__ Wcat)
{
  __shared__ float s[32][33];
  const int tx = threadIdx.x & 31;
  const int ty = threadIdx.x >> 5;      // 0..7
  const int nt = blockIdx.x * 32;       // n tile
  const int kt = blockIdx.y * 32;       // k tile (0..1023)
#pragma unroll
  for (int q = 0; q < 4; ++q) {
    int k = kt + q * 8 + ty;
    int n = nt + tx;
    float v = (k < HD) ? lw[(size_t)k * HD + n] : rw[(size_t)(k - HD) * HD + n];
    s[q * 8 + ty][tx] = v;
  }
  __syncthreads();
#pragma unroll
  for (int q = 0; q < 4; ++q) {
    int n = nt + q * 8 + ty;
    int k = kt + tx;
    Wcat[(size_t)n * (2 * HD) + k] = __float2bfloat16(s[tx][q * 8 + ty]);
  }
}

// ---------------- merged CSR build over concat'd [user | movie] dst space ----------------
__global__ void count2_k(const int* __restrict__ dmu, const int* __restrict__ dum,
                         int* __restrict__ cnt)
{
  for (int i = blockIdx.x * blockDim.x + threadIdx.x; i < NE; i += gridDim.x * blockDim.x) {
    atomicAdd(&cnt[dmu[i]], 1);
    atomicAdd(&cnt[NUU + dum[i]], 1);
  }
}

__global__ __launch_bounds__(512) void scan_a512(const int* __restrict__ in,
                                                 int* __restrict__ out,
                                                 int* __restrict__ bsum, int n)
{
  __shared__ int s[512];
  const int tid = threadIdx.x;
  const int i = blockIdx.x * 512 + tid;
  int v = (i < n) ? in[i] : 0;
  s[tid] = v;
  __syncthreads();
  for (int d = 1; d < 512; d <<= 1) {
    int t = (tid >= d) ? s[tid - d] : 0;
    __syncthreads();
    s[tid] += t;
    __syncthreads();
  }
  if (i < n) out[i] = s[tid] - v;           // exclusive
  if (tid == 511) bsum[blockIdx.x] = s[511];
}

__global__ void scan_b256(int* __restrict__ bsum, int nb)
{
  __shared__ int s[256];
  const int tid = threadIdx.x;
  int v = (tid < nb) ? bsum[tid] : 0;
  s[tid] = v;
  __syncthreads();
  for (int d = 1; d < 256; d <<= 1) {
    int t = (tid >= d) ? s[tid - d] : 0;
    __syncthreads();
    s[tid] += t;
    __syncthreads();
  }
  if (tid < nb) bsum[tid] = s[tid] - v;     // exclusive
}

__global__ __launch_bounds__(512) void scan_c512(int* __restrict__ out,
                                                 const int* __restrict__ bsum, int n)
{
  const int i = blockIdx.x * 512 + threadIdx.x;
  if (i < n) out[i] += bsum[blockIdx.x];
}

__global__ void fill2_k(const int* __restrict__ dmu, const int* __restrict__ dum,
                        const int* __restrict__ off, int* __restrict__ fill,
                        int* __restrict__ csr)
{
  for (int i = blockIdx.x * blockDim.x + threadIdx.x; i < NE; i += gridDim.x * blockDim.x) {
    int d0 = dmu[i];
    int p0 = off[d0] + atomicAdd(&fill[d0], 1);
    csr[p0] = i;
    int d1 = NUU + dum[i];
    int p1 = off[d1] + atomicAdd(&fill[d1], 1);
    csr[p1] = i;
  }
}

// ---- per-dst edge-attr sums over concat dst space: eaSum[d][0..6], pad [7]=0 ----
__global__ __launch_bounds__(256) void easum2_k(
    const float* __restrict__ eaMU, const float* __restrict__ eaUM,
    const int* __restrict__ csr, const int* __restrict__ off,
    const int* __restrict__ cnt, float* __restrict__ eaSum)
{
  const int g = threadIdx.x >> 3;
  const int cl = threadIdx.x & 7;
  const int d = blockIdx.x * 32 + g;
  if (d >= NT) return;
  const float* __restrict__ ea = (d < NUU) ? eaMU : eaUM;
  const int deg = cnt[d];
  const int start = off[d];
  float a = 0.f;
  for (int i = 0; i < deg; ++i) {
    int e = csr[start + i];
    if (cl < 7) a += ea[(size_t)e * EDIM + cl];
  }
  eaSum[(size_t)d * 8 + cl] = (cl < 7) ? a : 0.f;
}

// ---- folded classifier weights: Wl' = lw@cls, Wr' = rw@cls, cc = lb@cls ----
__global__ __launch_bounds__(64) void projw_k(
    const float* __restrict__ lw, const float* __restrict__ rw,
    const float* __restrict__ lb, const float* __restrict__ clsW,
    float* __restrict__ Wl, float* __restrict__ Wr, float* __restrict__ cc)
{
  const int k = blockIdx.x;
  const int l = threadIdx.x;
  if (k < HD) {
    float aL[NC] = {0, 0, 0, 0, 0, 0, 0};
    float aR[NC] = {0, 0, 0, 0, 0, 0, 0};
    for (int j = l; j < HD; j += 64) {
      float a = lw[(size_t)k * HD + j];
      float b = rw[(size_t)k * HD + j];
#pragma unroll
      for (int c = 0; c < NC; ++c) {
        float w = clsW[(size_t)j * NC + c];
        aL[c] += a * w;
        aR[c] += b * w;
      }
    }
#pragma unroll
    for (int c = 0; c < NC; ++c)
      for (int s = 32; s; s >>= 1) {
        aL[c] += __shfl_xor(aL[c], s);
        aR[c] += __shfl_xor(aR[c], s);
      }
    if (l == 0) {
#pragma unroll
      for (int c = 0; c < NC; ++c) {
        Wl[k * NC + c] = aL[c];
        Wr[k * NC + c] = aR[c];
      }
    }
  } else {
    float a0[NC] = {0, 0, 0, 0, 0, 0, 0};
    for (int j = l; j < HD; j += 64) {
      float a = lb[j];
#pragma unroll
      for (int c = 0; c < NC; ++c) a0[c] += a * clsW[(size_t)j * NC + c];
    }
#pragma unroll
    for (int c = 0; c < NC; ++c)
      for (int s = 32; s; s >>= 1) a0[c] += __shfl_xor(a0[c], s);
    if (l == 0) {
#pragma unroll
      for (int c = 0; c < NC; ++c) cc[c] = a0[c];
    }
  }
}

// ---- tiny fold: ewP[j][c] = ew[j]@Wl[:,c], ebP[c] = eb@Wl[:,c]; 8 waves ----
__global__ __launch_bounds__(512) void proj2_k(
    const float* __restrict__ ew, const float* __restrict__ ebv,
    const float* __restrict__ Wl, float* __restrict__ ewP, float* __restrict__ ebP)
{
  const int j = threadIdx.x >> 6;   // 0..7 (7 == eb row)
  const int l = threadIdx.x & 63;
  const float* __restrict__ src = (j < 7) ? &ew[(size_t)j * HD] : ebv;
  float acc[NC] = {0, 0, 0, 0, 0, 0, 0};
  for (int k = l; k < HD; k += 64) {
    float v = src[k];
#pragma unroll
    for (int c = 0; c < NC; ++c) acc[c] += v * Wl[(size_t)k * NC + c];
  }
#pragma unroll
  for (int c = 0; c < NC; ++c)
    for (int s = 32; s; s >>= 1) acc[c] += __shfl_xor(acc[c], s);
  if (l == 0) {
    if (j < 7) {
#pragma unroll
      for (int c = 0; c < NC; ++c) ewP[j * 8 + c] = acc[c];
      ewP[j * 8 + 7] = 0.f;
    } else {
#pragma unroll
      for (int c = 0; c < NC; ++c) ebP[c] = acc[c];
      ebP[7] = 0.f;
    }
  }
}

// ---- prep: W2t[16][512] bf16: rows 0..6 = WA^T, 7 = 0, 8..14 = WB^T, 15 = 0 ----
__global__ __launch_bounds__(256) void w2t_k(const float* __restrict__ WA,
                                             const float* __restrict__ WB,
                                             bf16* __restrict__ W2t)
{
  int idx = blockIdx.x * 256 + threadIdx.x;
  if (idx >= 16 * HD) return;
  int n = idx >> 9;
  int k = idx & (HD - 1);
  float v = 0.f;
  if (n < 7) v = WA[k * NC + n];
  else if (n >= 8 && n < 15) v = WB[k * NC + (n - 8)];
  W2t[(size_t)n * HD + k] = __float2bfloat16(v);
}

// ---- layer-2 aggregation in projected (7-dim) space; 8 lanes per dst ----
__global__ __launch_bounds__(256) void agg_proj_k(
    const float* __restrict__ srcP, const float* __restrict__ ownP,
    const int* __restrict__ esrc, const int* __restrict__ csr,
    const int* __restrict__ off, const int* __restrict__ cnt,
    const float* __restrict__ eaSum, const float* __restrict__ ewP,
    const float* __restrict__ ebP, const float* __restrict__ cc,
    float* __restrict__ P, int ndst)
{
  const int g = threadIdx.x >> 3;
  const int cl = threadIdx.x & 7;
  const int d = blockIdx.x * 32 + g;
  if (d >= ndst) return;
  const int deg = cnt[d];
  const int start = off[d];
  float a = 0.f;
  int i = 0;
  for (; i + 1 < deg; i += 2) {
    int e0 = csr[start + i], e1 = csr[start + i + 1];
    int s0 = esrc[e0], s1 = esrc[e1];
    a += srcP[(size_t)s0 * 8 + cl] + srcP[(size_t)s1 * 8 + cl];
  }
  if (i < deg) {
    int e = csr[start + i];
    a += srcP[(size_t)esrc[e] * 8 + cl];
  }
  float r = ownP[(size_t)d * 8 + cl] + ((cl < 7) ? cc[cl] : 0.f);
  if (deg > 0) {
    float inv = 1.f / (float)deg;
    float es = 0.f;
#pragma unroll
    for (int j = 0; j < NC; ++j) es += eaSum[(size_t)d * 8 + j] * ewP[j * 8 + cl];
    r += (a + es) * inv + ebP[cl];
  }
  if (cl < 7) P[(size_t)d * NC + cl] = r;
}

// ---- layer-1 SpMM: wave per dst, 16B/lane gathers, unroll-4; epilogue uses eaSum ----
__global__ __launch_bounds__(256) void spmm_t(
    const bf16* __restrict__ xsrc, const int* __restrict__ esrc,
    const int* __restrict__ csr, const int* __restrict__ off,
    const int* __restrict__ cnt, const float* __restrict__ eaSum,
    const float* __restrict__ ew, const float* __restrict__ eb,
    bf16* __restrict__ t, int ndst)
{
  const int lane = threadIdx.x & 63;
  const int d = blockIdx.x * 4 + (threadIdx.x >> 6);
  if (d >= ndst) return;
  const int deg = cnt[d];
  const int start = off[d];
  const int c0 = lane * 8;
  float acc[8] = {0.f, 0.f, 0.f, 0.f, 0.f, 0.f, 0.f, 0.f};
  int i = 0;
  for (; i + 3 < deg; i += 4) {
    int e0 = csr[start + i], e1 = csr[start + i + 1];
    int e2 = csr[start + i + 2], e3 = csr[start + i + 3];
    int s0 = esrc[e0], s1 = esrc[e1], s2 = esrc[e2], s3 = esrc[e3];
    short8 v0 = *(const short8*)&xsrc[(size_t)s0 * HD + c0];
    short8 v1 = *(const short8*)&xsrc[(size_t)s1 * HD + c0];
    short8 v2 = *(const short8*)&xsrc[(size_t)s2 * HD + c0];
    short8 v3 = *(const short8*)&xsrc[(size_t)s3 * HD + c0];
#pragma unroll
    for (int j = 0; j < 8; ++j)
      acc[j] += (b2f((unsigned short)v0[j]) + b2f((unsigned short)v1[j])) +
                (b2f((unsigned short)v2[j]) + b2f((unsigned short)v3[j]));
  }
  for (; i < deg; ++i) {
    int e = csr[start + i];
    int s = esrc[e];
    short8 v = *(const short8*)&xsrc[(size_t)s * HD + c0];
#pragma unroll
    for (int j = 0; j < 8; ++j) acc[j] += b2f((unsigned short)v[j]);
  }
  short8 sv;
  if (deg > 0) {
    const float inv = 1.f / (float)deg;
    float es[8] = {0.f, 0.f, 0.f, 0.f, 0.f, 0.f, 0.f, 0.f};
#pragma unroll
    for (int j = 0; j < NC; ++j) {
      const float av = eaSum[(size_t)d * 8 + j];
      const float* __restrict__ wr = &ew[(size_t)j * HD + c0];
#pragma unroll
      for (int jj = 0; jj < 8; ++jj) es[jj] += av * wr[jj];
    }
#pragma unroll
    for (int jj = 0; jj < 8; ++jj)
      sv[jj] = (short)f2bbits((acc[jj] + es[jj]) * inv + eb[c0 + jj]);
  } else {
#pragma unroll
    for (int jj = 0; jj < 8; ++jj) sv[jj] = (short)f2bbits(0.f);
  }
  *(short8*)&t[(size_t)d * HD + c0] = sv;
}

// ---- MFMA GEMM + fused dual 7-dim projection epilogue.
// z = [A1|A2] @ Wcat^T + bias; relu; Ppart[nt][row][16] += relu(z_blockcols) @ W2t^T.
// u1/m1 never materialized. Tile 128x128, BK=32, 4 waves, XCD-bijective swizzle.
__global__ __launch_bounds__(256) void gemm_mfma(
    const bf16* __restrict__ A1, const bf16* __restrict__ A2,
    const bf16* __restrict__ Wcat, const float* __restrict__ bias,
    const bf16* __restrict__ W2t, float* __restrict__ Ppart, int M)
{
  __shared__ __align__(16) char lds[34816];   // staging 16KB; epilogue z[128][136] bf16
  const int tid = threadIdx.x;
  const int lane = tid & 63;
  const int wid = tid >> 6;
  const int wr = wid >> 1, wc = wid & 1;
  const int lr = lane & 15, lk = lane >> 4;

  // XCD-bijective swizzle (m204), n-fastest decode
  const int nwg = gridDim.x;
  const int orig = blockIdx.x;
  const int q = nwg >> 3, r8 = nwg & 7;
  const int xcd = orig & 7, pos = orig >> 3;
  const int wg = (xcd < r8) ? xcd * (q + 1) + pos : r8 * (q + 1) + (xcd - r8) * q + pos;
  const int mt = wg >> 2, nt = wg & 3;
  const int m0 = mt * 128;
  const int n0 = nt * 128;

  const int srow = tid >> 2;        // 0..63
  const int sslot = tid & 3;

  f32x4 acc[4][4];
#pragma unroll
  for (int i = 0; i < 4; ++i)
#pragma unroll
    for (int j = 0; j < 4; ++j) acc[i][j] = (f32x4){0.f, 0.f, 0.f, 0.f};

  int gr0 = m0 + srow;       if (gr0 >= M) gr0 = M - 1;
  int gr1 = m0 + srow + 64;  if (gr1 >= M) gr1 = M - 1;
  const size_t aoff0 = (size_t)gr0 * HD + 8 * sslot;
  const size_t aoff1 = (size_t)gr1 * HD + 8 * sslot;
  const size_t boff0 = (size_t)(n0 + srow) * (2 * HD) + 8 * sslot;
  const size_t boff1 = (size_t)(n0 + srow + 64) * (2 * HD) + 8 * sslot;

  for (int ks = 0; ks < 32; ++ks) {
    const int k0 = ks * 32;
    const bf16* __restrict__ Ap = (k0 < HD) ? A1 : A2;
    const int ac = k0 & (HD - 1);
    gload16(Ap + aoff0 + ac, &lds[tid * 16]);
    gload16(Ap + aoff1 + ac, &lds[4096 + tid * 16]);
    gload16(Wcat + boff0 + k0, &lds[8192 + tid * 16]);
    gload16(Wcat + boff1 + k0, &lds[12288 + tid * 16]);
    __syncthreads();

    short8 af[4], bfr[4];
#pragma unroll
    for (int mf = 0; mf < 4; ++mf)
      af[mf] = *(const short8*)&lds[(wr * 64 + mf * 16 + lr) * 64 + lk * 16];
#pragma unroll
    for (int nf = 0; nf < 4; ++nf)
      bfr[nf] = *(const short8*)&lds[8192 + (wc * 64 + nf * 16 + lr) * 64 + lk * 16];
#pragma unroll
    for (int mf = 0; mf < 4; ++mf)
#pragma unroll
      for (int nf = 0; nf < 4; ++nf)
        acc[mf][nf] = __builtin_amdgcn_mfma_f32_16x16x32_bf16(
            af[mf], bfr[nf], acc[mf][nf], 0, 0, 0);
    __syncthreads();
  }

  // ---- epilogue: relu(z) -> LDS tile [128][136] bf16 ----
  bf16* zs = (bf16*)lds;
  const int ZLD = 136;
#pragma unroll
  for (int nf = 0; nf < 4; ++nf) {
    const int col_l = wc * 64 + nf * 16 + lr;
    const float bv = bias[n0 + col_l];
#pragma unroll
    for (int mf = 0; mf < 4; ++mf) {
      const int row_l = wr * 64 + mf * 16 + lk * 4;
#pragma unroll
      for (int r = 0; r < 4; ++r) {
        float v = fmaxf(acc[mf][nf][r] + bv, 0.f);
        zs[(size_t)(row_l + r) * ZLD + col_l] = __float2bfloat16(v);
      }
    }
  }
  __syncthreads();

  // ---- per-wave 32-row strip: Ppart[nt][row][0..15] = z_strip @ W2t^T ----
  const int strip = wid * 32;
  f32x4 p0 = {0.f, 0.f, 0.f, 0.f}, p1 = {0.f, 0.f, 0.f, 0.f};
#pragma unroll
  for (int kk = 0; kk < 4; ++kk) {
    short8 bfg = *(const short8*)&W2t[(size_t)lr * HD + n0 + kk * 32 + 8 * lk];
    short8 a0 = *(const short8*)&zs[(size_t)(strip + lr) * ZLD + kk * 32 + 8 * lk];
    short8 a1 = *(const short8*)&zs[(size_t)(strip + 16 + lr) * ZLD + kk * 32 + 8 * lk];
    p0 = __builtin_amdgcn_mfma_f32_16x16x32_bf16(a0, bfg, p0, 0, 0, 0);
    p1 = __builtin_amdgcn_mfma_f32_16x16x32_bf16(a1, bfg, p1, 0, 0, 0);
  }
#pragma unroll
  for (int r = 0; r < 4; ++r) {
    int row0 = m0 + strip + lk * 4 + r;
    if (row0 < M) Ppart[((size_t)nt * M + row0) * 16 + lr] = p0[r];
    int row1 = m0 + strip + 16 + lk * 4 + r;
    if (row1 < M) Ppart[((size_t)nt * M + row1) * 16 + lr] = p1[r];
  }
}

// ---- sum 4 n-tile partials, split into Pa[rows][8], Pb[rows][8] ----
__global__ __launch_bounds__(256) void reduce4_k(
    const float* __restrict__ PpU, const float* __restrict__ PpM,
    float* __restrict__ uPa, float* __restrict__ uPb,
    float* __restrict__ mPa, float* __restrict__ mPb)
{
  int idx = blockIdx.x * 256 + threadIdx.x;
  if (idx >= NT * 16) return;
  int row = idx >> 4, j = idx & 15;
  const float* Pp;
  float *Pa, *Pb;
  int rows, r;
  if (row < NUU) { Pp = PpU; Pa = uPa; Pb = uPb; rows = NUU; r = row; }
  else { Pp = PpM; Pa = mPa; Pb = mPb; rows = NMM; r = row - NUU; }
  float s = Pp[((size_t)0 * rows + r) * 16 + j] + Pp[((size_t)1 * rows + r) * 16 + j] +
            Pp[((size_t)2 * rows + r) * 16 + j] + Pp[((size_t)3 * rows + r) * 16 + j];
  if (j < 8) Pa[(size_t)r * 8 + j] = s;
  else Pb[(size_t)r * 8 + (j - 8)] = s;
}

__global__ void gather_out_k(const float* __restrict__ Pu, const float* __restrict__ Pm,
                             const int* __restrict__ eli, const float* __restrict__ cb,
                             float* __restrict__ out)
{
  const int i = blockIdx.x * 256 + threadIdx.x;
  if (i >= NEL * NC) return;
  int e = i / NC;
  int c = i - e * NC;
  out[i] = Pu[(size_t)eli[e] * NC + c] + Pm[(size_t)eli[NEL + e] * NC + c] + cb[c];
}

// ---------------- host side ----------------
static inline char* bump(char*& p, size_t bytes)
{
  char* r = p;
  p += (bytes + 255) & ~(size_t)255;
  return r;
}

extern "C" void kernel_launch(void* const* d_in, const int* in_sizes, int n_in,
                              void* d_out, int out_size, void* d_ws, size_t ws_size,
                              hipStream_t stream)
{
  const float* movie_x   = (const float*)d_in[0];
  const float* user_emb  = (const float*)d_in[1];
  const float* movie_emb = (const float*)d_in[2];
  const float* mlw       = (const float*)d_in[3];
  const float* mlb       = (const float*)d_in[4];
  const float* ea_um     = (const float*)d_in[5];
  const float* ea_mu     = (const float*)d_in[6];
  const float* mu1_lw = (const float*)d_in[7];
  const float* mu1_lb = (const float*)d_in[8];
  const float* mu1_rw = (const float*)d_in[9];
  const float* mu1_ew = (const float*)d_in[10];
  const float* mu1_eb = (const float*)d_in[11];
  const float* um1_lw = (const float*)d_in[12];
  const float* um1_lb = (const float*)d_in[13];
  const float* um1_rw = (const float*)d_in[14];
  const float* um1_ew = (const float*)d_in[15];
  const float* um1_eb = (const float*)d_in[16];
  const float* mu2_lw = (const float*)d_in[17];
  const float* mu2_lb = (const float*)d_in[18];
  const float* mu2_rw = (const float*)d_in[19];
  const float* mu2_ew = (const float*)d_in[20];
  const float* mu2_eb = (const float*)d_in[21];
  const float* um2_lw = (const float*)d_in[22];
  const float* um2_lb = (const float*)d_in[23];
  const float* um2_rw = (const float*)d_in[24];
  const float* um2_ew = (const float*)d_in[25];
  const float* um2_eb = (const float*)d_in[26];
  const float* cls_w  = (const float*)d_in[27];
  const float* cls_b  = (const float*)d_in[28];
  const int*   ei_um  = (const int*)d_in[29];   // [2, E]: src(user), dst(movie)
  const int*   ei_mu  = (const int*)d_in[30];   // [2, E]: src(movie), dst(user)
  const int*   eli    = (const int*)d_in[31];   // [2, EL]
  float* out = (float*)d_out;

  char* w = (char*)d_ws;
  bf16* x_m   = (bf16*)bump(w, (size_t)NMM * HD * 2);
  bf16* tbuf  = (bf16*)bump(w, (size_t)NUU * HD * 2);
  bf16* ue_bf = (bf16*)bump(w, (size_t)NUU * HD * 2);
  bf16* Wcat_u1 = (bf16*)bump(w, (size_t)HD * 2 * HD * 2);
  bf16* Wcat_m1 = (bf16*)bump(w, (size_t)HD * 2 * HD * 2);
  float* PpU  = (float*)bump(w, (size_t)4 * NUU * 16 * 4);
  float* PpM  = (float*)bump(w, (size_t)4 * NMM * 16 * 4);
  float* uPa  = (float*)bump(w, (size_t)NUU * 8 * 4);   // u1 @ Wl_m (src for movie-dst)
  float* uPb  = (float*)bump(w, (size_t)NUU * 8 * 4);   // u1 @ Wr_u (own for user-dst)
  float* mPa  = (float*)bump(w, (size_t)NMM * 8 * 4);   // m1 @ Wl_u (src for user-dst)
  float* mPb  = (float*)bump(w, (size_t)NMM * 8 * 4);   // m1 @ Wr_m (own for movie-dst)
  float* Pu   = (float*)bump(w, (size_t)NUU * NC * 4);
  float* Pm   = (float*)bump(w, (size_t)NMM * NC * 4);
  float* Wl_u = (float*)bump(w, (size_t)HD * NC * 4);
  float* Wr_u = (float*)bump(w, (size_t)HD * NC * 4);
  float* cc_u = (float*)bump(w, 64 * 4);
  float* Wl_m = (float*)bump(w, (size_t)HD * NC * 4);
  float* Wr_m = (float*)bump(w, (size_t)HD * NC * 4);
  float* cc_m = (float*)bump(w, 64 * 4);
  bf16* W2t_u = (bf16*)bump(w, (size_t)16 * HD * 2);
  bf16* W2t_m = (bf16*)bump(w, (size_t)16 * HD * 2);
  float* eaSum = (float*)bump(w, (size_t)NT * 8 * 4);
  float* ewP_u = (float*)bump(w, 64 * 4);
  float* ebP_u = (float*)bump(w, 64 * 4);
  float* ewP_m = (float*)bump(w, 64 * 4);
  float* ebP_m = (float*)bump(w, 64 * 4);
  int* cf     = (int*)bump(w, (size_t)2 * NT * 4);   // cnt | fill
  int* cnt    = cf;
  int* fill   = cf + NT;
  int* off    = (int*)bump(w, (size_t)NT * 4);
  int* bsum   = (int*)bump(w, 256 * 4);
  int* csr    = (int*)bump(w, (size_t)2 * NE * 4);

  const int GN = (NT + 511) / 512;    // 137 scan blocks

  hipMemsetAsync(cf, 0, (size_t)2 * NT * 4, stream);

  encoder_k<<<1024, 256, 0, stream>>>(movie_x, mlw, mlb, movie_emb, x_m);
  cvt_bf16_k<<<2048, 256, 0, stream>>>(user_emb, ue_bf, NUU * HD / 4);
  {
    dim3 g(HD / 32, 2 * HD / 32);
    wtrans_k<<<g, 256, 0, stream>>>(mu1_lw, mu1_rw, Wcat_u1);
    wtrans_k<<<g, 256, 0, stream>>>(um1_lw, um1_rw, Wcat_m1);
  }

  count2_k<<<1024, 256, 0, stream>>>(ei_mu + NE, ei_um + NE, cnt);
  scan_a512<<<GN, 512, 0, stream>>>(cnt, off, bsum, NT);
  scan_b256<<<1, 256, 0, stream>>>(bsum, GN);
  scan_c512<<<GN, 512, 0, stream>>>(off, bsum, NT);
  fill2_k<<<1024, 256, 0, stream>>>(ei_mu + NE, ei_um + NE, off, fill, csr);
  easum2_k<<<(NT + 31) / 32, 256, 0, stream>>>(ea_mu, ea_um, csr, off, cnt, eaSum);

  projw_k<<<HD + 1, 64, 0, stream>>>(mu2_lw, mu2_rw, mu2_lb, cls_w, Wl_u, Wr_u, cc_u);
  projw_k<<<HD + 1, 64, 0, stream>>>(um2_lw, um2_rw, um2_lb, cls_w + (size_t)HD * NC,
                                     Wl_m, Wr_m, cc_m);
  proj2_k<<<1, 512, 0, stream>>>(mu2_ew, mu2_eb, Wl_u, ewP_u, ebP_u);
  proj2_k<<<1, 512, 0, stream>>>(um2_ew, um2_eb, Wl_m, ewP_m, ebP_m);
  w2t_k<<<32, 256, 0, stream>>>(Wl_m, Wr_u, W2t_u);   // user gemm: A=Wl_m, B=Wr_u
  w2t_k<<<32, 256, 0, stream>>>(Wl_u, Wr_m, W2t_m);   // movie gemm: A=Wl_u, B=Wr_m

  const int nwgU = ((NUU + 127) / 128) * 4;   // 1564
  const int nwgM = ((NMM + 127) / 128) * 4;   // 628

  // layer 1 + fused layer-2 projections
  spmm_t<<<(NUU + 3) / 4, 256, 0, stream>>>(x_m, ei_mu, csr, off, cnt, eaSum,
                                            mu1_ew, mu1_eb, tbuf, NUU);
  gemm_mfma<<<nwgU, 256, 0, stream>>>(tbuf, ue_bf, Wcat_u1, mu1_lb, W2t_u, PpU, NUU);
  spmm_t<<<(NMM + 3) / 4, 256, 0, stream>>>(ue_bf, ei_um, csr, off + NUU, cnt + NUU,
                                            eaSum + (size_t)NUU * 8,
                                            um1_ew, um1_eb, tbuf, NMM);
  gemm_mfma<<<nwgM, 256, 0, stream>>>(tbuf, x_m, Wcat_m1, um1_lb, W2t_m, PpM, NMM);

  reduce4_k<<<(NT * 16 + 255) / 256, 256, 0, stream>>>(PpU, PpM, uPa, uPb, mPa, mPb);

  // layer-2 aggregation in 7-dim space
  agg_proj_k<<<(NUU + 31) / 32, 256, 0, stream>>>(mPa, uPb, ei_mu, csr, off, cnt,
                                                  eaSum, ewP_u, ebP_u, cc_u, Pu, NUU);
  agg_proj_k<<<(NMM + 31) / 32, 256, 0, stream>>>(uPa, mPb, ei_um, csr, off + NUU,
                                                  cnt + NUU, eaSum + (size_t)NUU * 8,
                                                  ewP_m, ebP_m, cc_m, Pm, NMM);

  gather_out_k<<<(NEL * NC + 255) / 256, 256, 0, stream>>>(Pu, Pm, eli, cls_b, out);
}

// Round 7
// 361.263 us; speedup vs baseline: 4.6948x; 1.1629x over previous
//
#include <hip/hip_runtime.h>
#include <hip/hip_bf16.h>

#define NUU 50000
#define NMM 20000
#define NT (NUU + NMM)
#define FEAT 32
#define NE 262144
#define NEL 100000
#define HD 512
#define EDIM 7
#define NC 7

typedef __hip_bfloat16 bf16;
typedef __attribute__((ext_vector_type(8))) short short8;
typedef __attribute__((ext_vector_type(4))) float f32x4;

__device__ __forceinline__ float b2f(unsigned short u)
{
  return __uint_as_float((unsigned)u << 16);
}
__device__ __forceinline__ unsigned short f2bbits(float x)
{
  __hip_bfloat16 h = __float2bfloat16(x);
  return *reinterpret_cast<unsigned short*>(&h);
}
__device__ __forceinline__ float2 ld2(const float* p) { return *(const float2*)p; }
__device__ __forceinline__ void st2b(bf16* p, float x, float y)
{
  ushort2 u = make_ushort2(f2bbits(x), f2bbits(y));
  *(ushort2*)p = u;
}
__device__ __forceinline__ void gload16(const void* g, void* l)
{
  __builtin_amdgcn_global_load_lds(
      (const __attribute__((address_space(1))) void*)g,
      (__attribute__((address_space(3))) void*)l, 16, 0, 0);
}

// ---- merged prep: blocks [0,1024) encoder; [1024,2048) fp32->bf16 cvt of user_emb ----
__global__ __launch_bounds__(256) void prep_k(
    const float* __restrict__ mx, const float* __restrict__ W,
    const float* __restrict__ b, const float* __restrict__ emb,
    bf16* __restrict__ xm, const float* __restrict__ uin, bf16* __restrict__ ubf)
{
  const int tid = threadIdx.x;
  if (blockIdx.x < 1024) {
    const int c0 = 2 * tid;
    float2 wreg[FEAT];
#pragma unroll
    for (int k = 0; k < FEAT; ++k) wreg[k] = ld2(&W[(size_t)k * HD + c0]);
    const float2 bv = ld2(&b[c0]);
    __shared__ float xr[FEAT];
    for (int m = blockIdx.x; m < NMM; m += 1024) {
      if (tid < FEAT) xr[tid] = mx[(size_t)m * FEAT + tid];
      __syncthreads();
      float2 e2 = ld2(&emb[(size_t)m * HD + c0]);
      float s0 = bv.x + e2.x, s1 = bv.y + e2.y;
#pragma unroll
      for (int k = 0; k < FEAT; ++k) {
        s0 += xr[k] * wreg[k].x;
        s1 += xr[k] * wreg[k].y;
      }
      st2b(&xm[(size_t)m * HD + c0], s0, s1);
      __syncthreads();
    }
  } else {
    const int n4 = NUU * HD / 4;
    for (int i = (blockIdx.x - 1024) * 256 + tid; i < n4; i += 1024 * 256) {
      float4 v = *(const float4*)&uin[4 * (size_t)i];
      ushort4 u = make_ushort4(f2bbits(v.x), f2bbits(v.y), f2bbits(v.z), f2bbits(v.w));
      *(ushort4*)&ubf[4 * (size_t)i] = u;
    }
  }
}

// ---- merged Wcat transpose (z picks param set) ----
__global__ __launch_bounds__(256) void wtrans_k(
    const float* __restrict__ lwA, const float* __restrict__ rwA, bf16* __restrict__ WcA,
    const float* __restrict__ lwB, const float* __restrict__ rwB, bf16* __restrict__ WcB)
{
  const float* lw = blockIdx.z ? lwB : lwA;
  const float* rw = blockIdx.z ? rwB : rwA;
  bf16* Wcat = blockIdx.z ? WcB : WcA;
  __shared__ float s[32][33];
  const int tx = threadIdx.x & 31;
  const int ty = threadIdx.x >> 5;
  const int nt = blockIdx.x * 32;
  const int kt = blockIdx.y * 32;
#pragma unroll
  for (int q = 0; q < 4; ++q) {
    int k = kt + q * 8 + ty;
    int n = nt + tx;
    float v = (k < HD) ? lw[(size_t)k * HD + n] : rw[(size_t)(k - HD) * HD + n];
    s[q * 8 + ty][tx] = v;
  }
  __syncthreads();
#pragma unroll
  for (int q = 0; q < 4; ++q) {
    int n = nt + q * 8 + ty;
    int k = kt + tx;
    Wcat[(size_t)n * (2 * HD) + k] = __float2bfloat16(s[tx][q * 8 + ty]);
  }
}

// ---------------- merged CSR build over concat'd [user | movie] dst space ----------------
__global__ void count2_k(const int* __restrict__ dmu, const int* __restrict__ dum,
                         int* __restrict__ cnt)
{
  for (int i = blockIdx.x * blockDim.x + threadIdx.x; i < NE; i += gridDim.x * blockDim.x) {
    atomicAdd(&cnt[dmu[i]], 1);
    atomicAdd(&cnt[NUU + dum[i]], 1);
  }
}

__global__ __launch_bounds__(512) void scan_a512(const int* __restrict__ in,
                                                 int* __restrict__ out,
                                                 int* __restrict__ bsum, int n)
{
  __shared__ int s[512];
  const int tid = threadIdx.x;
  const int i = blockIdx.x * 512 + tid;
  int v = (i < n) ? in[i] : 0;
  s[tid] = v;
  __syncthreads();
  for (int d = 1; d < 512; d <<= 1) {
    int t = (tid >= d) ? s[tid - d] : 0;
    __syncthreads();
    s[tid] += t;
    __syncthreads();
  }
  if (i < n) out[i] = s[tid] - v;           // exclusive
  if (tid == 511) bsum[blockIdx.x] = s[511];
}

__global__ void scan_b256(int* __restrict__ bsum, int nb)
{
  __shared__ int s[256];
  const int tid = threadIdx.x;
  int v = (tid < nb) ? bsum[tid] : 0;
  s[tid] = v;
  __syncthreads();
  for (int d = 1; d < 256; d <<= 1) {
    int t = (tid >= d) ? s[tid - d] : 0;
    __syncthreads();
    s[tid] += t;
    __syncthreads();
  }
  if (tid < nb) bsum[tid] = s[tid] - v;     // exclusive
}

__global__ __launch_bounds__(512) void scan_c512(int* __restrict__ out,
                                                 const int* __restrict__ bsum, int n)
{
  const int i = blockIdx.x * 512 + threadIdx.x;
  if (i < n) out[i] += bsum[blockIdx.x];
}

// fill CSR with BOTH edge id (for easum) and source node id (kills one indirection)
__global__ void fill2_k(const int* __restrict__ smu, const int* __restrict__ dmu,
                        const int* __restrict__ sum_, const int* __restrict__ dum,
                        const int* __restrict__ off, int* __restrict__ fill,
                        int* __restrict__ csrE, int* __restrict__ csrS)
{
  for (int i = blockIdx.x * blockDim.x + threadIdx.x; i < NE; i += gridDim.x * blockDim.x) {
    int d0 = dmu[i];
    int p0 = off[d0] + atomicAdd(&fill[d0], 1);
    csrE[p0] = i;
    csrS[p0] = smu[i];
    int d1 = NUU + dum[i];
    int p1 = off[d1] + atomicAdd(&fill[d1], 1);
    csrE[p1] = i;
    csrS[p1] = sum_[i];
  }
}

// ---- per-dst edge-attr sums over concat dst space: eaSum[d][0..6], pad [7]=0 ----
__global__ __launch_bounds__(256) void easum2_k(
    const float* __restrict__ eaMU, const float* __restrict__ eaUM,
    const int* __restrict__ csrE, const int* __restrict__ off,
    const int* __restrict__ cnt, float* __restrict__ eaSum)
{
  const int g = threadIdx.x >> 3;
  const int cl = threadIdx.x & 7;
  const int d = blockIdx.x * 32 + g;
  if (d >= NT) return;
  const float* __restrict__ ea = (d < NUU) ? eaMU : eaUM;
  const int deg = cnt[d];
  const int start = off[d];
  float a = 0.f;
  for (int i = 0; i < deg; ++i) {
    int e = csrE[start + i];
    if (cl < 7) a += ea[(size_t)e * EDIM + cl];
  }
  eaSum[(size_t)d * 8 + cl] = (cl < 7) ? a : 0.f;
}

// ---- folded classifier weights, both param sets in one launch (blockIdx.y) ----
__global__ __launch_bounds__(64) void projw_k(
    const float* __restrict__ lwA, const float* __restrict__ rwA,
    const float* __restrict__ lbA, const float* __restrict__ clsW,
    float* __restrict__ WlA, float* __restrict__ WrA, float* __restrict__ ccA,
    const float* __restrict__ lwB, const float* __restrict__ rwB,
    const float* __restrict__ lbB,
    float* __restrict__ WlB, float* __restrict__ WrB, float* __restrict__ ccB)
{
  const int side = blockIdx.y;
  const float* lw = side ? lwB : lwA;
  const float* rw = side ? rwB : rwA;
  const float* lb = side ? lbB : lbA;
  const float* cw = clsW + (side ? (size_t)HD * NC : 0);
  float* Wl = side ? WlB : WlA;
  float* Wr = side ? WrB : WrA;
  float* cc = side ? ccB : ccA;
  const int k = blockIdx.x;
  const int l = threadIdx.x;
  if (k < HD) {
    float aL[NC] = {0, 0, 0, 0, 0, 0, 0};
    float aR[NC] = {0, 0, 0, 0, 0, 0, 0};
    for (int j = l; j < HD; j += 64) {
      float a = lw[(size_t)k * HD + j];
      float b = rw[(size_t)k * HD + j];
#pragma unroll
      for (int c = 0; c < NC; ++c) {
        float w = cw[(size_t)j * NC + c];
        aL[c] += a * w;
        aR[c] += b * w;
      }
    }
#pragma unroll
    for (int c = 0; c < NC; ++c)
      for (int s = 32; s; s >>= 1) {
        aL[c] += __shfl_xor(aL[c], s);
        aR[c] += __shfl_xor(aR[c], s);
      }
    if (l == 0) {
#pragma unroll
      for (int c = 0; c < NC; ++c) {
        Wl[k * NC + c] = aL[c];
        Wr[k * NC + c] = aR[c];
      }
    }
  } else {
    float a0[NC] = {0, 0, 0, 0, 0, 0, 0};
    for (int j = l; j < HD; j += 64) {
      float a = lb[j];
#pragma unroll
      for (int c = 0; c < NC; ++c) a0[c] += a * cw[(size_t)j * NC + c];
    }
#pragma unroll
    for (int c = 0; c < NC; ++c)
      for (int s = 32; s; s >>= 1) a0[c] += __shfl_xor(a0[c], s);
    if (l == 0) {
#pragma unroll
      for (int c = 0; c < NC; ++c) cc[c] = a0[c];
    }
  }
}

// ---- tiny fold (both sides, 2 blocks): ewP[j][c] = ew[j]@Wl[:,c], ebP = eb@Wl ----
__global__ __launch_bounds__(512) void proj2_k(
    const float* __restrict__ ewA, const float* __restrict__ ebA,
    const float* __restrict__ WlA, float* __restrict__ ewPA, float* __restrict__ ebPA,
    const float* __restrict__ ewB, const float* __restrict__ ebB,
    const float* __restrict__ WlB, float* __restrict__ ewPB, float* __restrict__ ebPB)
{
  const int side = blockIdx.x;
  const float* ew = side ? ewB : ewA;
  const float* ebv = side ? ebB : ebA;
  const float* Wl = side ? WlB : WlA;
  float* ewP = side ? ewPB : ewPA;
  float* ebP = side ? ebPB : ebPA;
  const int j = threadIdx.x >> 6;
  const int l = threadIdx.x & 63;
  const float* __restrict__ src = (j < 7) ? &ew[(size_t)j * HD] : ebv;
  float acc[NC] = {0, 0, 0, 0, 0, 0, 0};
  for (int k = l; k < HD; k += 64) {
    float v = src[k];
#pragma unroll
    for (int c = 0; c < NC; ++c) acc[c] += v * Wl[(size_t)k * NC + c];
  }
#pragma unroll
  for (int c = 0; c < NC; ++c)
    for (int s = 32; s; s >>= 1) acc[c] += __shfl_xor(acc[c], s);
  if (l == 0) {
    if (j < 7) {
#pragma unroll
      for (int c = 0; c < NC; ++c) ewP[j * 8 + c] = acc[c];
      ewP[j * 8 + 7] = 0.f;
    } else {
#pragma unroll
      for (int c = 0; c < NC; ++c) ebP[c] = acc[c];
      ebP[7] = 0.f;
    }
  }
}

// ---- prep W2t (both sides): rows 0..6 = WA^T, 7 = 0, 8..14 = WB^T, 15 = 0 ----
__global__ __launch_bounds__(256) void w2t_k(
    const float* __restrict__ WAu, const float* __restrict__ WBu, bf16* __restrict__ W2u,
    const float* __restrict__ WAm, const float* __restrict__ WBm, bf16* __restrict__ W2m)
{
  int idx = blockIdx.x * 256 + threadIdx.x;
  if (idx >= 2 * 16 * HD) return;
  const int side = idx >= 16 * HD;
  if (side) idx -= 16 * HD;
  const float* WA = side ? WAm : WAu;
  const float* WB = side ? WBm : WBu;
  bf16* W2t = side ? W2m : W2u;
  int n = idx >> 9;
  int k = idx & (HD - 1);
  float v = 0.f;
  if (n < 7) v = WA[k * NC + n];
  else if (n >= 8 && n < 15) v = WB[k * NC + (n - 8)];
  W2t[(size_t)n * HD + k] = __float2bfloat16(v);
}

// ---- merged layer-2 aggregation (concat dst space); 8 lanes per dst ----
__global__ __launch_bounds__(256) void agg_all_k(
    const float* __restrict__ mPa, const float* __restrict__ uPb,
    const float* __restrict__ uPa, const float* __restrict__ mPb,
    const int* __restrict__ csrS, const int* __restrict__ off,
    const int* __restrict__ cnt, const float* __restrict__ eaSum,
    const float* __restrict__ ewP_u, const float* __restrict__ ebP_u,
    const float* __restrict__ cc_u, const float* __restrict__ ewP_m,
    const float* __restrict__ ebP_m, const float* __restrict__ cc_m,
    float* __restrict__ Pu, float* __restrict__ Pm)
{
  const int g = threadIdx.x >> 3;
  const int cl = threadIdx.x & 7;
  const int d = blockIdx.x * 32 + g;
  if (d >= NT) return;
  const int user = (d < NUU);
  const float* srcP = user ? mPa : uPa;
  const float* ownP = user ? uPb : mPb;
  const float* ewP = user ? ewP_u : ewP_m;
  const float* ebP = user ? ebP_u : ebP_m;
  const float* cc = user ? cc_u : cc_m;
  float* P = user ? Pu : Pm;
  const int dl = user ? d : d - NUU;
  const int deg = cnt[d];
  const int start = off[d];
  float a = 0.f;
  int i = 0;
  for (; i + 1 < deg; i += 2) {
    int s0 = csrS[start + i], s1 = csrS[start + i + 1];
    a += srcP[(size_t)s0 * 8 + cl] + srcP[(size_t)s1 * 8 + cl];
  }
  if (i < deg) a += srcP[(size_t)csrS[start + i] * 8 + cl];
  float r = ownP[(size_t)dl * 8 + cl] + ((cl < 7) ? cc[cl] : 0.f);
  if (deg > 0) {
    float inv = 1.f / (float)deg;
    float es = 0.f;
#pragma unroll
    for (int j = 0; j < NC; ++j) es += eaSum[(size_t)d * 8 + j] * ewP[j * 8 + cl];
    r += (a + es) * inv + ebP[cl];
  }
  if (cl < 7) P[(size_t)dl * NC + cl] = r;
}

// ---- merged layer-1 SpMM over concat dst space; direct src ids (csrS) ----
__global__ __launch_bounds__(256) void spmm_all_k(
    const bf16* __restrict__ x_m, const bf16* __restrict__ ue_bf,
    const int* __restrict__ csrS, const int* __restrict__ off,
    const int* __restrict__ cnt, const float* __restrict__ eaSum,
    const float* __restrict__ ew_u, const float* __restrict__ eb_u,
    const float* __restrict__ ew_m, const float* __restrict__ eb_m,
    bf16* __restrict__ t)
{
  const int lane = threadIdx.x & 63;
  const int d = blockIdx.x * 4 + (threadIdx.x >> 6);
  if (d >= NT) return;
  const int user = (d < NUU);
  const bf16* __restrict__ xsrc = user ? x_m : ue_bf;
  const float* __restrict__ ew = user ? ew_u : ew_m;
  const float* __restrict__ eb = user ? eb_u : eb_m;
  const int deg = cnt[d];
  const int start = off[d];
  const int c0 = lane * 8;
  float acc[8] = {0.f, 0.f, 0.f, 0.f, 0.f, 0.f, 0.f, 0.f};
  int i = 0;
  for (; i + 3 < deg; i += 4) {
    int s0 = csrS[start + i], s1 = csrS[start + i + 1];
    int s2 = csrS[start + i + 2], s3 = csrS[start + i + 3];
    short8 v0 = *(const short8*)&xsrc[(size_t)s0 * HD + c0];
    short8 v1 = *(const short8*)&xsrc[(size_t)s1 * HD + c0];
    short8 v2 = *(const short8*)&xsrc[(size_t)s2 * HD + c0];
    short8 v3 = *(const short8*)&xsrc[(size_t)s3 * HD + c0];
#pragma unroll
    for (int j = 0; j < 8; ++j)
      acc[j] += (b2f((unsigned short)v0[j]) + b2f((unsigned short)v1[j])) +
                (b2f((unsigned short)v2[j]) + b2f((unsigned short)v3[j]));
  }
  for (; i < deg; ++i) {
    int s = csrS[start + i];
    short8 v = *(const short8*)&xsrc[(size_t)s * HD + c0];
#pragma unroll
    for (int j = 0; j < 8; ++j) acc[j] += b2f((unsigned short)v[j]);
  }
  short8 sv;
  if (deg > 0) {
    const float inv = 1.f / (float)deg;
    float es[8] = {0.f, 0.f, 0.f, 0.f, 0.f, 0.f, 0.f, 0.f};
#pragma unroll
    for (int j = 0; j < NC; ++j) {
      const float av = eaSum[(size_t)d * 8 + j];
      const float* __restrict__ wr = &ew[(size_t)j * HD + c0];
#pragma unroll
      for (int jj = 0; jj < 8; ++jj) es[jj] += av * wr[jj];
    }
#pragma unroll
    for (int jj = 0; jj < 8; ++jj)
      sv[jj] = (short)f2bbits((acc[jj] + es[jj]) * inv + eb[c0 + jj]);
  } else {
#pragma unroll
    for (int jj = 0; jj < 8; ++jj) sv[jj] = (short)f2bbits(0.f);
  }
  *(short8*)&t[(size_t)d * HD + c0] = sv;
}

// ---- merged MFMA GEMM (user wgs then movie wgs) + fused dual 7-dim projection ----
__global__ __launch_bounds__(256) void gemm_all_k(
    const bf16* __restrict__ tbuf, const bf16* __restrict__ ue_bf,
    const bf16* __restrict__ x_m, const bf16* __restrict__ Wcat_u,
    const bf16* __restrict__ Wcat_m, const float* __restrict__ bias_u,
    const float* __restrict__ bias_m, const bf16* __restrict__ W2t_u,
    const bf16* __restrict__ W2t_m, float* __restrict__ PpU,
    float* __restrict__ PpM, int nwgU)
{
  __shared__ __align__(16) char lds[34816];
  const int tid = threadIdx.x;
  const int lane = tid & 63;
  const int wid = tid >> 6;
  const int wr = wid >> 1, wc = wid & 1;
  const int lr = lane & 15, lk = lane >> 4;

  // XCD-bijective swizzle over combined grid (m204)
  const int nwg = gridDim.x;
  const int orig = blockIdx.x;
  const int q = nwg >> 3, r8 = nwg & 7;
  const int xcd = orig & 7, pos = orig >> 3;
  const int wg = (xcd < r8) ? xcd * (q + 1) + pos : r8 * (q + 1) + (xcd - r8) * q + pos;

  const int user = (wg < nwgU);
  const int wl = user ? wg : wg - nwgU;
  const bf16* __restrict__ A1 = user ? tbuf : tbuf + (size_t)NUU * HD;
  const bf16* __restrict__ A2 = user ? ue_bf : x_m;
  const bf16* __restrict__ Wcat = user ? Wcat_u : Wcat_m;
  const float* __restrict__ bias = user ? bias_u : bias_m;
  const bf16* __restrict__ W2t = user ? W2t_u : W2t_m;
  float* __restrict__ Ppart = user ? PpU : PpM;
  const int M = user ? NUU : NMM;

  const int mt = wl >> 2, nt = wl & 3;
  const int m0 = mt * 128;
  const int n0 = nt * 128;

  const int srow = tid >> 2;
  const int sslot = tid & 3;

  f32x4 acc[4][4];
#pragma unroll
  for (int i = 0; i < 4; ++i)
#pragma unroll
    for (int j = 0; j < 4; ++j) acc[i][j] = (f32x4){0.f, 0.f, 0.f, 0.f};

  int gr0 = m0 + srow;       if (gr0 >= M) gr0 = M - 1;
  int gr1 = m0 + srow + 64;  if (gr1 >= M) gr1 = M - 1;
  const size_t aoff0 = (size_t)gr0 * HD + 8 * sslot;
  const size_t aoff1 = (size_t)gr1 * HD + 8 * sslot;
  const size_t boff0 = (size_t)(n0 + srow) * (2 * HD) + 8 * sslot;
  const size_t boff1 = (size_t)(n0 + srow + 64) * (2 * HD) + 8 * sslot;

  for (int ks = 0; ks < 32; ++ks) {
    const int k0 = ks * 32;
    const bf16* __restrict__ Ap = (k0 < HD) ? A1 : A2;
    const int ac = k0 & (HD - 1);
    gload16(Ap + aoff0 + ac, &lds[tid * 16]);
    gload16(Ap + aoff1 + ac, &lds[4096 + tid * 16]);
    gload16(Wcat + boff0 + k0, &lds[8192 + tid * 16]);
    gload16(Wcat + boff1 + k0, &lds[12288 + tid * 16]);
    __syncthreads();

    short8 af[4], bfr[4];
#pragma unroll
    for (int mf = 0; mf < 4; ++mf)
      af[mf] = *(const short8*)&lds[(wr * 64 + mf * 16 + lr) * 64 + lk * 16];
#pragma unroll
    for (int nf = 0; nf < 4; ++nf)
      bfr[nf] = *(const short8*)&lds[8192 + (wc * 64 + nf * 16 + lr) * 64 + lk * 16];
#pragma unroll
    for (int mf = 0; mf < 4; ++mf)
#pragma unroll
      for (int nf = 0; nf < 4; ++nf)
        acc[mf][nf] = __builtin_amdgcn_mfma_f32_16x16x32_bf16(
            af[mf], bfr[nf], acc[mf][nf], 0, 0, 0);
    __syncthreads();
  }

  // ---- epilogue: relu(z) -> LDS tile [128][136] bf16 ----
  bf16* zs = (bf16*)lds;
  const int ZLD = 136;
#pragma unroll
  for (int nf = 0; nf < 4; ++nf) {
    const int col_l = wc * 64 + nf * 16 + lr;
    const float bv = bias[n0 + col_l];
#pragma unroll
    for (int mf = 0; mf < 4; ++mf) {
      const int row_l = wr * 64 + mf * 16 + lk * 4;
#pragma unroll
      for (int r = 0; r < 4; ++r) {
        float v = fmaxf(acc[mf][nf][r] + bv, 0.f);
        zs[(size_t)(row_l + r) * ZLD + col_l] = __float2bfloat16(v);
      }
    }
  }
  __syncthreads();

  // ---- per-wave 32-row strip: Ppart[nt][row][0..15] = z_strip @ W2t^T ----
  const int strip = wid * 32;
  f32x4 p0 = {0.f, 0.f, 0.f, 0.f}, p1 = {0.f, 0.f, 0.f, 0.f};
#pragma unroll
  for (int kk = 0; kk < 4; ++kk) {
    short8 bfg = *(const short8*)&W2t[(size_t)lr * HD + n0 + kk * 32 + 8 * lk];
    short8 a0 = *(const short8*)&zs[(size_t)(strip + lr) * ZLD + kk * 32 + 8 * lk];
    short8 a1 = *(const short8*)&zs[(size_t)(strip + 16 + lr) * ZLD + kk * 32 + 8 * lk];
    p0 = __builtin_amdgcn_mfma_f32_16x16x32_bf16(a0, bfg, p0, 0, 0, 0);
    p1 = __builtin_amdgcn_mfma_f32_16x16x32_bf16(a1, bfg, p1, 0, 0, 0);
  }
#pragma unroll
  for (int r = 0; r < 4; ++r) {
    int row0 = m0 + strip + lk * 4 + r;
    if (row0 < M) Ppart[((size_t)nt * M + row0) * 16 + lr] = p0[r];
    int row1 = m0 + strip + 16 + lk * 4 + r;
    if (row1 < M) Ppart[((size_t)nt * M + row1) * 16 + lr] = p1[r];
  }
}

// ---- sum 4 n-tile partials, split into Pa[rows][8], Pb[rows][8] ----
__global__ __launch_bounds__(256) void reduce4_k(
    const float* __restrict__ PpU, const float* __restrict__ PpM,
    float* __restrict__ uPa, float* __restrict__ uPb,
    float* __restrict__ mPa, float* __restrict__ mPb)
{
  int idx = blockIdx.x * 256 + threadIdx.x;
  if (idx >= NT * 16) return;
  int row = idx >> 4, j = idx & 15;
  const float* Pp;
  float *Pa, *Pb;
  int rows, r;
  if (row < NUU) { Pp = PpU; Pa = uPa; Pb = uPb; rows = NUU; r = row; }
  else { Pp = PpM; Pa = mPa; Pb = mPb; rows = NMM; r = row - NUU; }
  float s = Pp[((size_t)0 * rows + r) * 16 + j] + Pp[((size_t)1 * rows + r) * 16 + j] +
            Pp[((size_t)2 * rows + r) * 16 + j] + Pp[((size_t)3 * rows + r) * 16 + j];
  if (j < 8) Pa[(size_t)r * 8 + j] = s;
  else Pb[(size_t)r * 8 + (j - 8)] = s;
}

__global__ void gather_out_k(const float* __restrict__ Pu, const float* __restrict__ Pm,
                             const int* __restrict__ eli, const float* __restrict__ cb,
                             float* __restrict__ out)
{
  const int i = blockIdx.x * 256 + threadIdx.x;
  if (i >= NEL * NC) return;
  int e = i / NC;
  int c = i - e * NC;
  out[i] = Pu[(size_t)eli[e] * NC + c] + Pm[(size_t)eli[NEL + e] * NC + c] + cb[c];
}

// ---------------- host side ----------------
static inline char* bump(char*& p, size_t bytes)
{
  char* r = p;
  p += (bytes + 255) & ~(size_t)255;
  return r;
}

extern "C" void kernel_launch(void* const* d_in, const int* in_sizes, int n_in,
                              void* d_out, int out_size, void* d_ws, size_t ws_size,
                              hipStream_t stream)
{
  const float* movie_x   = (const float*)d_in[0];
  const float* user_emb  = (const float*)d_in[1];
  const float* movie_emb = (const float*)d_in[2];
  const float* mlw       = (const float*)d_in[3];
  const float* mlb       = (const float*)d_in[4];
  const float* ea_um     = (const float*)d_in[5];
  const float* ea_mu     = (const float*)d_in[6];
  const float* mu1_lw = (const float*)d_in[7];
  const float* mu1_lb = (const float*)d_in[8];
  const float* mu1_rw = (const float*)d_in[9];
  const float* mu1_ew = (const float*)d_in[10];
  const float* mu1_eb = (const float*)d_in[11];
  const float* um1_lw = (const float*)d_in[12];
  const float* um1_lb = (const float*)d_in[13];
  const float* um1_rw = (const float*)d_in[14];
  const float* um1_ew = (const float*)d_in[15];
  const float* um1_eb = (const float*)d_in[16];
  const float* mu2_lw = (const float*)d_in[17];
  const float* mu2_lb = (const float*)d_in[18];
  const float* mu2_rw = (const float*)d_in[19];
  const float* mu2_ew = (const float*)d_in[20];
  const float* mu2_eb = (const float*)d_in[21];
  const float* um2_lw = (const float*)d_in[22];
  const float* um2_lb = (const float*)d_in[23];
  const float* um2_rw = (const float*)d_in[24];
  const float* um2_ew = (const float*)d_in[25];
  const float* um2_eb = (const float*)d_in[26];
  const float* cls_w  = (const float*)d_in[27];
  const float* cls_b  = (const float*)d_in[28];
  const int*   ei_um  = (const int*)d_in[29];   // [2, E]: src(user), dst(movie)
  const int*   ei_mu  = (const int*)d_in[30];   // [2, E]: src(movie), dst(user)
  const int*   eli    = (const int*)d_in[31];   // [2, EL]
  float* out = (float*)d_out;

  char* w = (char*)d_ws;
  bf16* x_m   = (bf16*)bump(w, (size_t)NMM * HD * 2);
  bf16* tbuf  = (bf16*)bump(w, (size_t)NT * HD * 2);    // concat: user rows | movie rows
  bf16* ue_bf = (bf16*)bump(w, (size_t)NUU * HD * 2);
  bf16* Wcat_u1 = (bf16*)bump(w, (size_t)HD * 2 * HD * 2);
  bf16* Wcat_m1 = (bf16*)bump(w, (size_t)HD * 2 * HD * 2);
  float* PpU  = (float*)bump(w, (size_t)4 * NUU * 16 * 4);
  float* PpM  = (float*)bump(w, (size_t)4 * NMM * 16 * 4);
  float* uPa  = (float*)bump(w, (size_t)NUU * 8 * 4);   // u1 @ Wl_m (src for movie-dst)
  float* uPb  = (float*)bump(w, (size_t)NUU * 8 * 4);   // u1 @ Wr_u (own for user-dst)
  float* mPa  = (float*)bump(w, (size_t)NMM * 8 * 4);   // m1 @ Wl_u (src for user-dst)
  float* mPb  = (float*)bump(w, (size_t)NMM * 8 * 4);   // m1 @ Wr_m (own for movie-dst)
  float* Pu   = (float*)bump(w, (size_t)NUU * NC * 4);
  float* Pm   = (float*)bump(w, (size_t)NMM * NC * 4);
  float* Wl_u = (float*)bump(w, (size_t)HD * NC * 4);
  float* Wr_u = (float*)bump(w, (size_t)HD * NC * 4);
  float* cc_u = (float*)bump(w, 64 * 4);
  float* Wl_m = (float*)bump(w, (size_t)HD * NC * 4);
  float* Wr_m = (float*)bump(w, (size_t)HD * NC * 4);
  float* cc_m = (float*)bump(w, 64 * 4);
  bf16* W2t_u = (bf16*)bump(w, (size_t)16 * HD * 2);
  bf16* W2t_m = (bf16*)bump(w, (size_t)16 * HD * 2);
  float* eaSum = (float*)bump(w, (size_t)NT * 8 * 4);
  float* ewP_u = (float*)bump(w, 64 * 4);
  float* ebP_u = (float*)bump(w, 64 * 4);
  float* ewP_m = (float*)bump(w, 64 * 4);
  float* ebP_m = (float*)bump(w, 64 * 4);
  int* cf     = (int*)bump(w, (size_t)2 * NT * 4);   // cnt | fill
  int* cnt    = cf;
  int* fill   = cf + NT;
  int* off    = (int*)bump(w, (size_t)NT * 4);
  int* bsum   = (int*)bump(w, 256 * 4);
  int* csrE   = (int*)bump(w, (size_t)2 * NE * 4);
  int* csrS   = (int*)bump(w, (size_t)2 * NE * 4);

  const int GN = (NT + 511) / 512;    // 137 scan blocks

  hipMemsetAsync(cf, 0, (size_t)2 * NT * 4, stream);

  prep_k<<<2048, 256, 0, stream>>>(movie_x, mlw, mlb, movie_emb, x_m, user_emb, ue_bf);
  {
    dim3 g(HD / 32, 2 * HD / 32, 2);
    wtrans_k<<<g, 256, 0, stream>>>(mu1_lw, mu1_rw, Wcat_u1, um1_lw, um1_rw, Wcat_m1);
  }

  count2_k<<<1024, 256, 0, stream>>>(ei_mu + NE, ei_um + NE, cnt);
  scan_a512<<<GN, 512, 0, stream>>>(cnt, off, bsum, NT);
  scan_b256<<<1, 256, 0, stream>>>(bsum, GN);
  scan_c512<<<GN, 512, 0, stream>>>(off, bsum, NT);
  fill2_k<<<1024, 256, 0, stream>>>(ei_mu, ei_mu + NE, ei_um, ei_um + NE,
                                    off, fill, csrE, csrS);
  easum2_k<<<(NT + 31) / 32, 256, 0, stream>>>(ea_mu, ea_um, csrE, off, cnt, eaSum);

  {
    dim3 g(HD + 1, 2);
    projw_k<<<g, 64, 0, stream>>>(mu2_lw, mu2_rw, mu2_lb, cls_w, Wl_u, Wr_u, cc_u,
                                  um2_lw, um2_rw, um2_lb, Wl_m, Wr_m, cc_m);
  }
  proj2_k<<<2, 512, 0, stream>>>(mu2_ew, mu2_eb, Wl_u, ewP_u, ebP_u,
                                 um2_ew, um2_eb, Wl_m, ewP_m, ebP_m);
  w2t_k<<<64, 256, 0, stream>>>(Wl_m, Wr_u, W2t_u, Wl_u, Wr_m, W2t_m);

  // layer 1 (both sides, one launch each stage)
  spmm_all_k<<<(NT + 3) / 4, 256, 0, stream>>>(x_m, ue_bf, csrS, off, cnt, eaSum,
                                               mu1_ew, mu1_eb, um1_ew, um1_eb, tbuf);
  const int nwgU = ((NUU + 127) / 128) * 4;   // 1564
  const int nwgM = ((NMM + 127) / 128) * 4;   // 628
  gemm_all_k<<<nwgU + nwgM, 256, 0, stream>>>(tbuf, ue_bf, x_m, Wcat_u1, Wcat_m1,
                                              mu1_lb, um1_lb, W2t_u, W2t_m,
                                              PpU, PpM, nwgU);

  reduce4_k<<<(NT * 16 + 255) / 256, 256, 0, stream>>>(PpU, PpM, uPa, uPb, mPa, mPb);

  agg_all_k<<<(NT + 31) / 32, 256, 0, stream>>>(mPa, uPb, uPa, mPb, csrS, off, cnt,
                                                eaSum, ewP_u, ebP_u, cc_u,
                                                ewP_m, ebP_m, cc_m, Pu, Pm);

  gather_out_k<<<(NEL * NC + 255) / 256, 256, 0, stream>>>(Pu, Pm, eli, cls_b, out);
}